// Round 13
// baseline (162.796 us; speedup 1.0000x reference)
//
#include <hip/hip_runtime.h>
#include <math.h>

#define DM   1024
#define DI   2048
#define DS   16
#define DTR  64
#define NB   2
#define SEQL 1024
#define NTOK (NB*SEQL)
#define XND  96   /* DTR + 2*DS */
#define XNP  128  /* padded xproj width */
#define CK   128  /* scan chunks */
#define CL   8    /* chunk length */

typedef __bf16 bf16x8 __attribute__((ext_vector_type(8)));
typedef __bf16 bf16x4 __attribute__((ext_vector_type(4)));
typedef float  f32x4  __attribute__((ext_vector_type(4)));

// ------------- fused prep: zeroing + conversions + transposes ----------------
#define PREP_BLOCKS 3872

__device__ inline void trans_tile64(const float* __restrict__ W,
                                    __bf16* __restrict__ WT, int K, int N,
                                    int n0, int k0, int tid, __bf16 (*t)[65])
{
    const int tx = tid & 63, ty = tid >> 6;   // ty 0..3
    #pragma unroll
    for (int i = 0; i < 16; i++)
        t[ty * 16 + i][tx] = (__bf16)W[(size_t)(k0 + ty * 16 + i) * N + n0 + tx];
    __syncthreads();
    #pragma unroll
    for (int i = 0; i < 16; i++)
        WT[(size_t)(n0 + ty * 16 + i) * K + k0 + tx] = t[tx][ty * 16 + i];
}

__global__ __launch_bounds__(256) void prep(
    const float* __restrict__ x, const float* __restrict__ W_in,
    const float* __restrict__ W_out, const float* __restrict__ W_dt,
    const float* __restrict__ W_xprj,
    __bf16* __restrict__ xb, __bf16* __restrict__ W_inT,
    __bf16* __restrict__ W_outT, __bf16* __restrict__ WdtT,
    __bf16* __restrict__ W_xprT, float* __restrict__ xdbl)
{
    __shared__ __bf16 t[64][65];
    int bid = blockIdx.x;
    const int tid = threadIdx.x;

    if (bid < 256) {                        // R0: zero xdbl
        const int i = bid * 1024 + tid * 4;
        const float4 z = {0.f, 0.f, 0.f, 0.f};
        *reinterpret_cast<float4*>(&xdbl[i]) = z;
        return;
    }
    bid -= 256;
    if (bid < 1024) {                       // R1: cvt x -> xb
        const int e = (bid * 256 + tid) * 8;
        const float4 v0 = *reinterpret_cast<const float4*>(&x[e]);
        const float4 v1 = *reinterpret_cast<const float4*>(&x[e + 4]);
        bf16x8 o;
        o[0] = (__bf16)v0.x; o[1] = (__bf16)v0.y; o[2] = (__bf16)v0.z; o[3] = (__bf16)v0.w;
        o[4] = (__bf16)v1.x; o[5] = (__bf16)v1.y; o[6] = (__bf16)v1.z; o[7] = (__bf16)v1.w;
        *reinterpret_cast<bf16x8*>(&xb[e]) = o;
        return;
    }
    bid -= 1024;
    if (bid < 1024) {                       // R2: W_in [1024][4096] -> T
        trans_tile64(W_in, W_inT, DM, 2 * DI, (bid & 63) * 64, (bid >> 6) * 64, tid, t);
        return;
    }
    bid -= 1024;
    if (bid < 512) {                        // R3: W_out [2048][1024] -> T
        trans_tile64(W_out, W_outT, DI, DM, (bid & 15) * 64, (bid >> 4) * 64, tid, t);
        return;
    }
    bid -= 512;
    if (bid < 32) {                         // R4: W_dt [64][2048] -> T
        trans_tile64(W_dt, WdtT, DTR, DI, bid * 64, 0, tid, t);
        return;
    }
    bid -= 32;
    {                                       // R5: xproj transpose+pad
        const int idx = bid * 256 + tid;
        const int k = idx & (DI - 1);
        const int n = idx >> 11;
        W_xprT[(size_t)n * DI + k] = (n < XND) ? (__bf16)W_xprj[(size_t)k * XND + n]
                                               : (__bf16)0.f;
    }
}

// -------- bf16 MFMA GEMM, 128xTN tile, BK=64, XOR-swizzled LDS ---------------
// Single-buffered 2-barrier loop (round-8 proven structure); occupancy comes
// from blocks/CU (grid), which TN=64 doubles vs TN=128.
// MODE 0: store f32 | 1: atomicAdd f32 | 2: A from f32 [.][128] cols 0..63
// reg-staged+cvt, softplus(acc+bias)->bf16 | 3: store bf16 (per-z partials).
// SWZ 0: none | 1: XCD swizzle row-major | 2: XCD swizzle col-major.
template<int MODE, int SWZ, int TN>
__global__ __launch_bounds__(256) void gemm_bf16(
    const __bf16* __restrict__ A, const __bf16* __restrict__ Bt,
    void* __restrict__ Cp, int M, int N, int K, int ldc,
    const float* __restrict__ bias)
{
    constexpr int NFR = TN / 32;            // n-fragments per wave per ks
    __shared__ __bf16 As[128 * 64];
    __shared__ __bf16 Bs[TN * 64];
    const int tid  = threadIdx.x;
    const int lane = tid & 63;
    const int wid  = tid >> 6;
    const int wr   = wid >> 1, wc = wid & 1;

    int bx = blockIdx.x, by = blockIdx.y;
    if (SWZ != 0) {
        const int gx = gridDim.x, gy = gridDim.y;
        const int nxy = gx * gy;            // multiple of 8
        const int q = nxy >> 3;
        int lin = by * gx + bx;
        lin = (lin & 7) * q + (lin >> 3);
        if (SWZ == 1) { by = lin / gx; bx = lin % gx; }
        else          { bx = lin / gy; by = lin % gy; }
    }
    const int brow = by * 128, bcol = bx * TN;
    const int kper = K / gridDim.z;
    const int kbeg = blockIdx.z * kper, kend = kbeg + kper;

    f32x4 acc[4][NFR] = {};

    for (int k0 = kbeg; k0 < kend; k0 += 64) {
        __syncthreads();
        // ---- stage A (128 rows x 64 k) ----
        if (MODE == 2) {
            const float* Af = reinterpret_cast<const float*>(A);
            #pragma unroll
            for (int p = 0; p < 4; p++) {
                const int i = p * 256 + tid;
                const int r = i >> 3;
                const int j = i & 7;
                const float4 v0 = *reinterpret_cast<const float4*>(
                    &Af[(size_t)(brow + r) * XNP + j * 8]);
                const float4 v1 = *reinterpret_cast<const float4*>(
                    &Af[(size_t)(brow + r) * XNP + j * 8 + 4]);
                bf16x8 o;
                o[0] = (__bf16)v0.x; o[1] = (__bf16)v0.y; o[2] = (__bf16)v0.z; o[3] = (__bf16)v0.w;
                o[4] = (__bf16)v1.x; o[5] = (__bf16)v1.y; o[6] = (__bf16)v1.z; o[7] = (__bf16)v1.w;
                *reinterpret_cast<bf16x8*>(&As[r * 64 + ((j ^ (r & 7))) * 8]) = o;
            }
        } else {
            #pragma unroll
            for (int p = 0; p < 4; p++) {
                const int i = p * 256 + tid;
                const int r = i >> 3;
                const int gc = ((i & 7) ^ (r & 7)) * 8;
                __builtin_amdgcn_global_load_lds(
                    (const __attribute__((address_space(1))) void*)(A + (size_t)(brow + r) * K + k0 + gc),
                    (__attribute__((address_space(3))) void*)(&As[i * 8]), 16, 0, 0);
            }
        }
        // ---- stage B (TN rows x 64 k) ----
        #pragma unroll
        for (int p = 0; p < TN / 32; p++) {
            const int i = p * 256 + tid;
            const int r = i >> 3;
            const int gc = ((i & 7) ^ (r & 7)) * 8;
            __builtin_amdgcn_global_load_lds(
                (const __attribute__((address_space(1))) void*)(Bt + (size_t)(bcol + r) * K + k0 + gc),
                (__attribute__((address_space(3))) void*)(&Bs[i * 8]), 16, 0, 0);
        }
        __syncthreads();
        bf16x8 a[2][4], b[2][NFR];
        const int rA = wr * 64 + (lane & 15);
        const int rB = wc * (TN / 2) + (lane & 15);
        const int cq = lane >> 4;
        const int rx = lane & 7;
        #pragma unroll
        for (int ks = 0; ks < 2; ks++) {
            const int sl = ((ks * 4 + cq) ^ rx) * 8;
            #pragma unroll
            for (int m = 0; m < 4; m++)
                a[ks][m] = *reinterpret_cast<const bf16x8*>(&As[(rA + m * 16) * 64 + sl]);
            #pragma unroll
            for (int n = 0; n < NFR; n++)
                b[ks][n] = *reinterpret_cast<const bf16x8*>(&Bs[(rB + n * 16) * 64 + sl]);
        }
        #pragma unroll
        for (int ks = 0; ks < 2; ks++)
            #pragma unroll
            for (int m = 0; m < 4; m++)
                #pragma unroll
                for (int n = 0; n < NFR; n++)
                    acc[m][n] = __builtin_amdgcn_mfma_f32_16x16x32_bf16(
                        a[ks][m], b[ks][n], acc[m][n], 0, 0, 0);
    }
    const int crow = brow + wr * 64 + (lane >> 4) * 4;
    const int ccol = bcol + wc * (TN / 2) + (lane & 15);
    __bf16* Cb3 = (__bf16*)Cp + (size_t)blockIdx.z * ((MODE == 3) ? (size_t)M * ldc : 0);
    #pragma unroll
    for (int m = 0; m < 4; m++)
        #pragma unroll
        for (int n = 0; n < NFR; n++) {
            const int col = ccol + n * 16;
            #pragma unroll
            for (int j = 0; j < 4; j++) {
                const size_t idx = (size_t)(crow + m * 16 + j) * ldc + col;
                if (MODE == 0) {
                    ((float*)Cp)[idx] = acc[m][n][j];
                } else if (MODE == 1) {
                    atomicAdd(&((float*)Cp)[idx], acc[m][n][j]);
                } else if (MODE == 2) {
                    const float v = acc[m][n][j] + bias[col];
                    ((__bf16*)Cp)[idx] =
                        (__bf16)(fmaxf(v, 0.f) + log1pf(__expf(-fabsf(v))));
                } else {
                    Cb3[idx] = (__bf16)acc[m][n][j];
                }
            }
        }
}

// -------- depthwise causal conv (k=4) + bias + SiLU, 8 ch/thread -------------
__global__ __launch_bounds__(256) void conv_silu(
    const __bf16* __restrict__ xzb, const float* __restrict__ conv_w,
    const float* __restrict__ conv_b, __bf16* __restrict__ xcb)
{
    const int g  = blockIdx.x * 256 + threadIdx.x;
    const int d0 = (g & 255) * 8;
    const int tok = g >> 8;
    const int t   = tok & (SEQL - 1);

    float4 wv[8];
    #pragma unroll
    for (int j = 0; j < 8; j++)
        wv[j] = *reinterpret_cast<const float4*>(&conv_w[(d0 + j) * 4]);
    float acc[8];
    {
        const float4 b0 = *reinterpret_cast<const float4*>(&conv_b[d0]);
        const float4 b1 = *reinterpret_cast<const float4*>(&conv_b[d0 + 4]);
        acc[0] = b0.x; acc[1] = b0.y; acc[2] = b0.z; acc[3] = b0.w;
        acc[4] = b1.x; acc[5] = b1.y; acc[6] = b1.z; acc[7] = b1.w;
    }
    #pragma unroll
    for (int k = 0; k < 4; k++) {
        const int tt = t + k - 3;
        if (tt >= 0) {
            const bf16x8 v = *reinterpret_cast<const bf16x8*>(
                &xzb[(size_t)(tok + k - 3) * (2 * DI) + d0]);
            #pragma unroll
            for (int j = 0; j < 8; j++) {
                const float wk = (k == 0) ? wv[j].x : (k == 1) ? wv[j].y
                               : (k == 2) ? wv[j].z : wv[j].w;
                acc[j] += (float)v[j] * wk;
            }
        }
    }
    bf16x8 o;
    #pragma unroll
    for (int j = 0; j < 8; j++) {
        const float a = acc[j];
        o[j] = (__bf16)(a / (1.f + __expf(-a)));
    }
    *reinterpret_cast<bf16x8*>(&xcb[(size_t)g * 8]) = o;
}

// -------- scan pass A: per-chunk local scan from h=0, bf16 h out -------------
__global__ __launch_bounds__(256) void scan_partial(
    const __bf16* __restrict__ xcb, const float* __restrict__ xdbl,
    const __bf16* __restrict__ dtb, const float* __restrict__ A_log,
    __bf16* __restrict__ hpart, float* __restrict__ sdtb)
{
    __shared__ float Bsh[CL][16];
    const int tid = threadIdx.x;
    const int d = blockIdx.x * 256 + tid;
    const int c = blockIdx.y, b = blockIdx.z;
    const size_t base = (size_t)b * SEQL + c * CL;
    {
        const int st = tid >> 4, sg = tid & 15;
        if (st < CL) Bsh[st][sg] = xdbl[(base + st) * XNP + DTR + sg];
    }
    float dtv[CL], xcv[CL];
    #pragma unroll
    for (int t = 0; t < CL; t++) {
        dtv[t] = (float)dtb[(base + t) * DI + d];
        xcv[t] = (float)xcb[(base + t) * DI + d];
    }
    float Av[16];
    #pragma unroll
    for (int i = 0; i < 4; i++) {
        const float4 v = *reinterpret_cast<const float4*>(&A_log[(size_t)d * 16 + i * 4]);
        Av[i*4+0] = -__expf(v.x); Av[i*4+1] = -__expf(v.y);
        Av[i*4+2] = -__expf(v.z); Av[i*4+3] = -__expf(v.w);
    }
    __syncthreads();
    float h[16] = {};
    float sdt = 0.f;
    #pragma unroll
    for (int t = 0; t < CL; t++) {
        sdt += dtv[t];
        const float dx = dtv[t] * xcv[t];
        #pragma unroll
        for (int n = 0; n < 16; n++)
            h[n] = __expf(dtv[t] * Av[n]) * h[n] + dx * Bsh[t][n];
    }
    const size_t ob = ((size_t)(b * CK + c) * DI + d) * 16;
    bf16x8 o0, o1;
    #pragma unroll
    for (int i = 0; i < 8; i++) { o0[i] = (__bf16)h[i]; o1[i] = (__bf16)h[i + 8]; }
    *reinterpret_cast<bf16x8*>(&hpart[ob])     = o0;
    *reinterpret_cast<bf16x8*>(&hpart[ob + 8]) = o1;
    sdtb[(size_t)(b * CK + c) * DI + d] = sdt;
}

// -------- scan pass B: chunk combine, hpart -> hentry (bf16), batched --------
__global__ __launch_bounds__(256) void scan_combine(
    const float* __restrict__ A_log, const float* __restrict__ sdtb,
    const __bf16* __restrict__ hpart, __bf16* __restrict__ hentry)
{
    const int idx = blockIdx.x * 256 + threadIdx.x;
    const int n = idx & 15;
    const int d = (idx >> 4) & (DI - 1);
    const int b = idx >> 15;
    const float A = -__expf(A_log[(size_t)d * 16 + n]);
    float h = 0.f;
    for (int cb = 0; cb < CK / 16; cb++) {
        float hl[16], sv[16];
        #pragma unroll
        for (int j = 0; j < 16; j++) {
            const int c = cb * 16 + j;
            hl[j] = (float)hpart[((size_t)(b * CK + c) * DI + d) * 16 + n];
            sv[j] = sdtb[(size_t)(b * CK + c) * DI + d];
        }
        #pragma unroll
        for (int j = 0; j < 16; j++) {
            const int c = cb * 16 + j;
            hentry[((size_t)(b * CK + c) * DI + d) * 16 + n] = (__bf16)h;
            h = __expf(A * sv[j]) * h + hl[j];
        }
    }
}

// -------- scan pass C: seeded re-scan, emit y (D-skip + z-gate) as bf16 ------
__global__ __launch_bounds__(256) void scan_final(
    const __bf16* __restrict__ xzb, const __bf16* __restrict__ xcb,
    const float* __restrict__ xdbl, const __bf16* __restrict__ dtb,
    const float* __restrict__ A_log, const float* __restrict__ Dp,
    const __bf16* __restrict__ hentry, __bf16* __restrict__ yb)
{
    __shared__ float Bsh[CL][16];
    __shared__ float Csh[CL][16];
    const int tid = threadIdx.x;
    const int d = blockIdx.x * 256 + tid;
    const int c = blockIdx.y, b = blockIdx.z;
    const size_t base = (size_t)b * SEQL + c * CL;
    {
        const int st = tid >> 4, sg = tid & 15;
        if (st < CL)
            Bsh[st][sg] = xdbl[(base + st) * XNP + DTR + sg];
        else if (st < 2 * CL)
            Csh[st - CL][sg] = xdbl[(base + st - CL) * XNP + DTR + DS + sg];
    }
    float dtv[CL], xcv[CL], zv[CL];
    #pragma unroll
    for (int t = 0; t < CL; t++) {
        dtv[t] = (float)dtb[(base + t) * DI + d];
        xcv[t] = (float)xcb[(base + t) * DI + d];
        zv[t]  = (float)xzb[(base + t) * (2 * DI) + DI + d];
    }
    float Av[16];
    #pragma unroll
    for (int i = 0; i < 4; i++) {
        const float4 v = *reinterpret_cast<const float4*>(&A_log[(size_t)d * 16 + i * 4]);
        Av[i*4+0] = -__expf(v.x); Av[i*4+1] = -__expf(v.y);
        Av[i*4+2] = -__expf(v.z); Av[i*4+3] = -__expf(v.w);
    }
    float h[16];
    const size_t ob = ((size_t)(b * CK + c) * DI + d) * 16;
    {
        const bf16x8 v0 = *reinterpret_cast<const bf16x8*>(&hentry[ob]);
        const bf16x8 v1 = *reinterpret_cast<const bf16x8*>(&hentry[ob + 8]);
        #pragma unroll
        for (int i = 0; i < 8; i++) { h[i] = (float)v0[i]; h[i + 8] = (float)v1[i]; }
    }
    const float Dv = Dp[d];
    __syncthreads();
    #pragma unroll
    for (int t = 0; t < CL; t++) {
        const float dx = dtv[t] * xcv[t];
        float y = 0.f;
        #pragma unroll
        for (int n = 0; n < 16; n++) {
            h[n] = __expf(dtv[t] * Av[n]) * h[n] + dx * Bsh[t][n];
            y += h[n] * Csh[t][n];
        }
        y += xcv[t] * Dv;
        y *= zv[t] / (1.f + __expf(-zv[t]));
        yb[(base + t) * DI + d] = (__bf16)y;
    }
}

// -------- out = x + LayerNorm(sum of 4 bf16 partials) ------------------------
__global__ __launch_bounds__(256) void ln_add(
    const float* __restrict__ x, const __bf16* __restrict__ mpart,
    const float* __restrict__ gamma, const float* __restrict__ beta,
    float* __restrict__ out)
{
    const int tok = blockIdx.x;
    const int tid = threadIdx.x;
    const int lane = tid & 63, wave = tid >> 6;
    __shared__ float red[4];
    __shared__ float stats[2];

    float4 v = {0.f, 0.f, 0.f, 0.f};
    #pragma unroll
    for (int p = 0; p < 4; p++) {
        const bf16x4 mv = *reinterpret_cast<const bf16x4*>(
            &mpart[((size_t)p * NTOK + tok) * DM + tid * 4]);
        v.x += (float)mv[0]; v.y += (float)mv[1];
        v.z += (float)mv[2]; v.w += (float)mv[3];
    }
    float s = v.x + v.y + v.z + v.w;
    #pragma unroll
    for (int o = 32; o > 0; o >>= 1) s += __shfl_down(s, o, 64);
    if (lane == 0) red[wave] = s;
    __syncthreads();
    if (tid == 0) stats[0] = (red[0] + red[1] + red[2] + red[3]) * (1.f / DM);
    __syncthreads();
    const float mu = stats[0];
    const float dx = v.x - mu, dy = v.y - mu, dz = v.z - mu, dw = v.w - mu;
    float q = dx * dx + dy * dy + dz * dz + dw * dw;
    #pragma unroll
    for (int o = 32; o > 0; o >>= 1) q += __shfl_down(q, o, 64);
    if (lane == 0) red[wave] = q;
    __syncthreads();
    if (tid == 0)
        stats[1] = rsqrtf((red[0] + red[1] + red[2] + red[3]) * (1.f / DM) + 1e-6f);
    __syncthreads();
    const float rs = stats[1];

    const float4 g  = reinterpret_cast<const float4*>(gamma)[tid];
    const float4 bb = reinterpret_cast<const float4*>(beta)[tid];
    const float4 xv = reinterpret_cast<const float4*>(&x[(size_t)tok * DM])[tid];
    float4 o;
    o.x = xv.x + dx * rs * g.x + bb.x;
    o.y = xv.y + dy * rs * g.y + bb.y;
    o.z = xv.z + dz * rs * g.z + bb.z;
    o.w = xv.w + dw * rs * g.w + bb.w;
    reinterpret_cast<float4*>(&out[(size_t)tok * DM])[tid] = o;
}

extern "C" void kernel_launch(void* const* d_in, const int* in_sizes, int n_in,
                              void* d_out, int out_size, void* d_ws, size_t ws_size,
                              hipStream_t stream)
{
    const float* x      = (const float*)d_in[0];
    const float* W_in   = (const float*)d_in[1];
    const float* conv_w = (const float*)d_in[2];
    const float* conv_b = (const float*)d_in[3];
    const float* W_xprj = (const float*)d_in[4];
    const float* W_dt   = (const float*)d_in[5];
    const float* b_dt   = (const float*)d_in[6];
    const float* A_log  = (const float*)d_in[7];
    const float* D_par  = (const float*)d_in[8];
    const float* W_out  = (const float*)d_in[9];
    const float* gamma  = (const float*)d_in[10];
    const float* beta   = (const float*)d_in[11];
    float* out = (float*)d_out;

    // workspace layout (byte offsets, non-aliasing, ~113 MB)
    char* w = (char*)d_ws;
    __bf16* xzb    = (__bf16*)(w + 0);          // 16 MB [NTOK][4096] (xi|z)
    __bf16* xcb    = (__bf16*)(w + 16777216);   //  8 MB [NTOK][DI]
    float*  xdbl   = (float*) (w + 25165824);   //  1 MB [NTOK][128]
    __bf16* dtb    = (__bf16*)(w + 26214400);   //  8 MB [NTOK][DI]
    __bf16* mpart  = (__bf16*)(w + 34603008);   // 16 MB [4][NTOK][DM]
    __bf16* hpart  = (__bf16*)(w + 51380224);   // 16 MB [NB*CK][DI][16]
    __bf16* hentry = (__bf16*)(w + 68157440);   // 16 MB [NB*CK][DI][16]
    float*  sdtb   = (float*) (w + 84934656);   //  2 MB [NB*CK][DI]
    __bf16* xb     = (__bf16*)(w + 87031808);   //  4 MB [NTOK][DM]
    __bf16* W_inT  = (__bf16*)(w + 91226112);   //  8 MB [4096][DM]
    __bf16* W_outT = (__bf16*)(w + 99614720);   //  4 MB [DM][DI]
    __bf16* W_xprT = (__bf16*)(w + 103809024);  // .5 MB [128][DI]
    __bf16* WdtT   = (__bf16*)(w + 104333312);  // .25MB [DI][64]
    __bf16* yb     = (__bf16*)(w + 104595456);  //  8 MB [NTOK][DI]

    // 0. fused prep
    prep<<<PREP_BLOCKS, 256, 0, stream>>>(
        x, W_in, W_out, W_dt, W_xprj, xb, W_inT, W_outT, WdtT, W_xprT, xdbl);

    // 1. xz = x @ W_in  (M=2048, N=4096, K=1024) -> bf16, TN=64 -> 1024 blocks
    gemm_bf16<3, 2, 64><<<dim3(64, 16, 1), 256, 0, stream>>>(
        xb, W_inT, xzb, NTOK, 2 * DI, DM, 2 * DI, nullptr);

    // 2. conv + silu -> bf16
    conv_silu<<<(NTOK * DI / 8) / 256, 256, 0, stream>>>(xzb, conv_w, conv_b, xcb);

    // 3. x_dbl = xc @ W_xproj  (N=128 pad, K=2048), split-K=16, atomic f32
    gemm_bf16<1, 0, 128><<<dim3(1, 16, 16), 256, 0, stream>>>(
        xcb, W_xprT, xdbl, NTOK, XNP, DI, XNP, nullptr);

    // 4. dt = softplus(dt_r @ W_dt + b_dt) -> bf16, TN=64 -> 512 blocks
    gemm_bf16<2, 0, 64><<<dim3(32, 16, 1), 256, 0, stream>>>(
        (const __bf16*)xdbl, WdtT, dtb, NTOK, DI, DTR, DI, b_dt);

    // 5. chunked selective scan (CK=128 chunks of CL=8 -> 2048 blocks A/C)
    scan_partial<<<dim3(DI / 256, CK, NB), 256, 0, stream>>>(
        xcb, xdbl, dtb, A_log, hpart, sdtb);
    scan_combine<<<NB * DI * DS / 256, 256, 0, stream>>>(A_log, sdtb, hpart, hentry);
    scan_final<<<dim3(DI / 256, CK, NB), 256, 0, stream>>>(
        xzb, xcb, xdbl, dtb, A_log, D_par, hentry, yb);

    // 6. m partials = y @ W_out  (split-K=4, TN=64 -> 1024 blocks, bf16 partials)
    gemm_bf16<3, 1, 64><<<dim3(16, 16, 4), 256, 0, stream>>>(
        yb, W_outT, mpart, NTOK, DM, DI, DM, nullptr);

    // 7. out = x + LN(sum of partials)
    ln_add<<<NTOK, 256, 0, stream>>>(x, mpart, gamma, beta, out);
}

// Round 14
// 162.778 us; speedup vs baseline: 1.0001x; 1.0001x over previous
//
#include <hip/hip_runtime.h>
#include <math.h>

#define DM   1024
#define DI   2048
#define DS   16
#define DTR  64
#define NB   2
#define SEQL 1024
#define NTOK (NB*SEQL)
#define XND  96   /* DTR + 2*DS */
#define XNP  128  /* padded xproj width */
#define CK   128  /* scan chunks */
#define CL   8    /* chunk length */

typedef __bf16 bf16x8 __attribute__((ext_vector_type(8)));
typedef __bf16 bf16x4 __attribute__((ext_vector_type(4)));
typedef float  f32x4  __attribute__((ext_vector_type(4)));

// ------------- fused prep: zeroing + conversions + transposes ----------------
#define PREP_BLOCKS 3872

__device__ inline void trans_tile64(const float* __restrict__ W,
                                    __bf16* __restrict__ WT, int K, int N,
                                    int n0, int k0, int tid, __bf16 (*t)[65])
{
    const int tx = tid & 63, ty = tid >> 6;   // ty 0..3
    #pragma unroll
    for (int i = 0; i < 16; i++)
        t[ty * 16 + i][tx] = (__bf16)W[(size_t)(k0 + ty * 16 + i) * N + n0 + tx];
    __syncthreads();
    #pragma unroll
    for (int i = 0; i < 16; i++)
        WT[(size_t)(n0 + ty * 16 + i) * K + k0 + tx] = t[tx][ty * 16 + i];
}

__global__ __launch_bounds__(256) void prep(
    const float* __restrict__ x, const float* __restrict__ W_in,
    const float* __restrict__ W_out, const float* __restrict__ W_dt,
    const float* __restrict__ W_xprj,
    __bf16* __restrict__ xb, __bf16* __restrict__ W_inT,
    __bf16* __restrict__ W_outT, __bf16* __restrict__ WdtT,
    __bf16* __restrict__ W_xprT, float* __restrict__ xdbl)
{
    __shared__ __bf16 t[64][65];
    int bid = blockIdx.x;
    const int tid = threadIdx.x;

    if (bid < 256) {                        // R0: zero xdbl
        const int i = bid * 1024 + tid * 4;
        const float4 z = {0.f, 0.f, 0.f, 0.f};
        *reinterpret_cast<float4*>(&xdbl[i]) = z;
        return;
    }
    bid -= 256;
    if (bid < 1024) {                       // R1: cvt x -> xb
        const int e = (bid * 256 + tid) * 8;
        const float4 v0 = *reinterpret_cast<const float4*>(&x[e]);
        const float4 v1 = *reinterpret_cast<const float4*>(&x[e + 4]);
        bf16x8 o;
        o[0] = (__bf16)v0.x; o[1] = (__bf16)v0.y; o[2] = (__bf16)v0.z; o[3] = (__bf16)v0.w;
        o[4] = (__bf16)v1.x; o[5] = (__bf16)v1.y; o[6] = (__bf16)v1.z; o[7] = (__bf16)v1.w;
        *reinterpret_cast<bf16x8*>(&xb[e]) = o;
        return;
    }
    bid -= 1024;
    if (bid < 1024) {                       // R2: W_in [1024][4096] -> T
        trans_tile64(W_in, W_inT, DM, 2 * DI, (bid & 63) * 64, (bid >> 6) * 64, tid, t);
        return;
    }
    bid -= 1024;
    if (bid < 512) {                        // R3: W_out [2048][1024] -> T
        trans_tile64(W_out, W_outT, DI, DM, (bid & 15) * 64, (bid >> 4) * 64, tid, t);
        return;
    }
    bid -= 512;
    if (bid < 32) {                         // R4: W_dt [64][2048] -> T
        trans_tile64(W_dt, WdtT, DTR, DI, bid * 64, 0, tid, t);
        return;
    }
    bid -= 32;
    {                                       // R5: xproj transpose+pad
        const int idx = bid * 256 + tid;
        const int k = idx & (DI - 1);
        const int n = idx >> 11;
        W_xprT[(size_t)n * DI + k] = (n < XND) ? (__bf16)W_xprj[(size_t)k * XND + n]
                                               : (__bf16)0.f;
    }
}

// -------- bf16 MFMA GEMM, 128xTN tile, BK=64, XOR-swizzled LDS ---------------
// Single-buffered 2-barrier loop. MODE 1: atomicAdd f32 (direct stores).
// MODE 2: A from f32 [.][128] cols 0..63 reg-staged+cvt, softplus(acc+bias)
// -> bf16 via LDS-bounce coalesced store. MODE 3: bf16 via LDS-bounce
// (per-z partial offset when gridDim.z>1). LDS-bounce fixes the 2x HBM
// write amplification of 2B fragment-scattered stores (32B/64B-line).
// SWZ 0: none | 1: XCD swizzle row-major | 2: XCD swizzle col-major.
template<int MODE, int SWZ, int TN>
__global__ __launch_bounds__(256) void gemm_bf16(
    const __bf16* __restrict__ A, const __bf16* __restrict__ Bt,
    void* __restrict__ Cp, int M, int N, int K, int ldc,
    const float* __restrict__ bias)
{
    constexpr int NFR = TN / 32;            // n-fragments per wave per ks
    __shared__ __bf16 smem[128 * 64 + TN * 64];
    __bf16* As = smem;
    __bf16* Bs = smem + 128 * 64;
    const int tid  = threadIdx.x;
    const int lane = tid & 63;
    const int wid  = tid >> 6;
    const int wr   = wid >> 1, wc = wid & 1;

    int bx = blockIdx.x, by = blockIdx.y;
    if (SWZ != 0) {
        const int gx = gridDim.x, gy = gridDim.y;
        const int nxy = gx * gy;            // multiple of 8
        const int q = nxy >> 3;
        int lin = by * gx + bx;
        lin = (lin & 7) * q + (lin >> 3);
        if (SWZ == 1) { by = lin / gx; bx = lin % gx; }
        else          { bx = lin / gy; by = lin % gy; }
    }
    const int brow = by * 128, bcol = bx * TN;
    const int kper = K / gridDim.z;
    const int kbeg = blockIdx.z * kper, kend = kbeg + kper;

    f32x4 acc[4][NFR] = {};

    for (int k0 = kbeg; k0 < kend; k0 += 64) {
        __syncthreads();
        // ---- stage A (128 rows x 64 k) ----
        if (MODE == 2) {
            const float* Af = reinterpret_cast<const float*>(A);
            #pragma unroll
            for (int p = 0; p < 4; p++) {
                const int i = p * 256 + tid;
                const int r = i >> 3;
                const int j = i & 7;
                const float4 v0 = *reinterpret_cast<const float4*>(
                    &Af[(size_t)(brow + r) * XNP + j * 8]);
                const float4 v1 = *reinterpret_cast<const float4*>(
                    &Af[(size_t)(brow + r) * XNP + j * 8 + 4]);
                bf16x8 o;
                o[0] = (__bf16)v0.x; o[1] = (__bf16)v0.y; o[2] = (__bf16)v0.z; o[3] = (__bf16)v0.w;
                o[4] = (__bf16)v1.x; o[5] = (__bf16)v1.y; o[6] = (__bf16)v1.z; o[7] = (__bf16)v1.w;
                *reinterpret_cast<bf16x8*>(&As[r * 64 + ((j ^ (r & 7))) * 8]) = o;
            }
        } else {
            #pragma unroll
            for (int p = 0; p < 4; p++) {
                const int i = p * 256 + tid;
                const int r = i >> 3;
                const int gc = ((i & 7) ^ (r & 7)) * 8;
                __builtin_amdgcn_global_load_lds(
                    (const __attribute__((address_space(1))) void*)(A + (size_t)(brow + r) * K + k0 + gc),
                    (__attribute__((address_space(3))) void*)(&As[i * 8]), 16, 0, 0);
            }
        }
        // ---- stage B (TN rows x 64 k) ----
        #pragma unroll
        for (int p = 0; p < TN / 32; p++) {
            const int i = p * 256 + tid;
            const int r = i >> 3;
            const int gc = ((i & 7) ^ (r & 7)) * 8;
            __builtin_amdgcn_global_load_lds(
                (const __attribute__((address_space(1))) void*)(Bt + (size_t)(bcol + r) * K + k0 + gc),
                (__attribute__((address_space(3))) void*)(&Bs[i * 8]), 16, 0, 0);
        }
        __syncthreads();
        bf16x8 a[2][4], b[2][NFR];
        const int rA = wr * 64 + (lane & 15);
        const int rB = wc * (TN / 2) + (lane & 15);
        const int cq = lane >> 4;
        const int rx = lane & 7;
        #pragma unroll
        for (int ks = 0; ks < 2; ks++) {
            const int sl = ((ks * 4 + cq) ^ rx) * 8;
            #pragma unroll
            for (int m = 0; m < 4; m++)
                a[ks][m] = *reinterpret_cast<const bf16x8*>(&As[(rA + m * 16) * 64 + sl]);
            #pragma unroll
            for (int n = 0; n < NFR; n++)
                b[ks][n] = *reinterpret_cast<const bf16x8*>(&Bs[(rB + n * 16) * 64 + sl]);
        }
        #pragma unroll
        for (int ks = 0; ks < 2; ks++)
            #pragma unroll
            for (int m = 0; m < 4; m++)
                #pragma unroll
                for (int n = 0; n < NFR; n++)
                    acc[m][n] = __builtin_amdgcn_mfma_f32_16x16x32_bf16(
                        a[ks][m], b[ks][n], acc[m][n], 0, 0, 0);
    }
    const int crl = wr * 64 + (lane >> 4) * 4;   // local row base
    const int ccl = wc * (TN / 2) + (lane & 15); // local col base

    if (MODE == 1) {
        #pragma unroll
        for (int m = 0; m < 4; m++)
            #pragma unroll
            for (int n = 0; n < NFR; n++) {
                const int col = bcol + ccl + n * 16;
                #pragma unroll
                for (int j = 0; j < 4; j++)
                    atomicAdd(&((float*)Cp)[(size_t)(brow + crl + m * 16 + j) * ldc + col],
                              acc[m][n][j]);
            }
    } else {
        // ---- LDS-bounce epilogue: fragment -> LDS -> coalesced bf16x8 ----
        __syncthreads();                     // all LDS frag reads done
        __bf16* Cs = smem;                   // 128*TN bf16 fits (TN<=128)
        #pragma unroll
        for (int m = 0; m < 4; m++)
            #pragma unroll
            for (int n = 0; n < NFR; n++) {
                #pragma unroll
                for (int j = 0; j < 4; j++) {
                    float v = acc[m][n][j];
                    if (MODE == 2) {
                        v += bias[bcol + ccl + n * 16];
                        v = fmaxf(v, 0.f) + log1pf(__expf(-fabsf(v)));
                    }
                    Cs[(crl + m * 16 + j) * TN + ccl + n * 16] = (__bf16)v;
                }
            }
        __syncthreads();
        __bf16* Cb = (__bf16*)Cp +
            (size_t)blockIdx.z * ((MODE == 3) ? (size_t)M * ldc : 0);
        constexpr int CHUNKS = 128 * TN / 8;        // bf16x8 chunks in tile
        #pragma unroll
        for (int p = 0; p < CHUNKS / 256; p++) {
            const int i = p * 256 + tid;
            const int r = i / (TN / 8);
            const int cc = (i % (TN / 8)) * 8;
            *reinterpret_cast<bf16x8*>(&Cb[(size_t)(brow + r) * ldc + bcol + cc]) =
                *reinterpret_cast<const bf16x8*>(&Cs[r * TN + cc]);
        }
    }
}

// -------- depthwise causal conv (k=4) + bias + SiLU, 8 ch/thread -------------
__global__ __launch_bounds__(256) void conv_silu(
    const __bf16* __restrict__ xzb, const float* __restrict__ conv_w,
    const float* __restrict__ conv_b, __bf16* __restrict__ xcb)
{
    const int g  = blockIdx.x * 256 + threadIdx.x;
    const int d0 = (g & 255) * 8;
    const int tok = g >> 8;
    const int t   = tok & (SEQL - 1);

    float4 wv[8];
    #pragma unroll
    for (int j = 0; j < 8; j++)
        wv[j] = *reinterpret_cast<const float4*>(&conv_w[(d0 + j) * 4]);
    float acc[8];
    {
        const float4 b0 = *reinterpret_cast<const float4*>(&conv_b[d0]);
        const float4 b1 = *reinterpret_cast<const float4*>(&conv_b[d0 + 4]);
        acc[0] = b0.x; acc[1] = b0.y; acc[2] = b0.z; acc[3] = b0.w;
        acc[4] = b1.x; acc[5] = b1.y; acc[6] = b1.z; acc[7] = b1.w;
    }
    #pragma unroll
    for (int k = 0; k < 4; k++) {
        const int tt = t + k - 3;
        if (tt >= 0) {
            const bf16x8 v = *reinterpret_cast<const bf16x8*>(
                &xzb[(size_t)(tok + k - 3) * (2 * DI) + d0]);
            #pragma unroll
            for (int j = 0; j < 8; j++) {
                const float wk = (k == 0) ? wv[j].x : (k == 1) ? wv[j].y
                               : (k == 2) ? wv[j].z : wv[j].w;
                acc[j] += (float)v[j] * wk;
            }
        }
    }
    bf16x8 o;
    #pragma unroll
    for (int j = 0; j < 8; j++) {
        const float a = acc[j];
        o[j] = (__bf16)(a / (1.f + __expf(-a)));
    }
    *reinterpret_cast<bf16x8*>(&xcb[(size_t)g * 8]) = o;
}

// -------- scan pass A: per-chunk local scan from h=0, bf16 h out -------------
__global__ __launch_bounds__(256) void scan_partial(
    const __bf16* __restrict__ xcb, const float* __restrict__ xdbl,
    const __bf16* __restrict__ dtb, const float* __restrict__ A_log,
    __bf16* __restrict__ hpart, float* __restrict__ sdtb)
{
    __shared__ float Bsh[CL][16];
    const int tid = threadIdx.x;
    const int d = blockIdx.x * 256 + tid;
    const int c = blockIdx.y, b = blockIdx.z;
    const size_t base = (size_t)b * SEQL + c * CL;
    {
        const int st = tid >> 4, sg = tid & 15;
        if (st < CL) Bsh[st][sg] = xdbl[(base + st) * XNP + DTR + sg];
    }
    float dtv[CL], xcv[CL];
    #pragma unroll
    for (int t = 0; t < CL; t++) {
        dtv[t] = (float)dtb[(base + t) * DI + d];
        xcv[t] = (float)xcb[(base + t) * DI + d];
    }
    float Av[16];
    #pragma unroll
    for (int i = 0; i < 4; i++) {
        const float4 v = *reinterpret_cast<const float4*>(&A_log[(size_t)d * 16 + i * 4]);
        Av[i*4+0] = -__expf(v.x); Av[i*4+1] = -__expf(v.y);
        Av[i*4+2] = -__expf(v.z); Av[i*4+3] = -__expf(v.w);
    }
    __syncthreads();
    float h[16] = {};
    float sdt = 0.f;
    #pragma unroll
    for (int t = 0; t < CL; t++) {
        sdt += dtv[t];
        const float dx = dtv[t] * xcv[t];
        #pragma unroll
        for (int n = 0; n < 16; n++)
            h[n] = __expf(dtv[t] * Av[n]) * h[n] + dx * Bsh[t][n];
    }
    const size_t ob = ((size_t)(b * CK + c) * DI + d) * 16;
    bf16x8 o0, o1;
    #pragma unroll
    for (int i = 0; i < 8; i++) { o0[i] = (__bf16)h[i]; o1[i] = (__bf16)h[i + 8]; }
    *reinterpret_cast<bf16x8*>(&hpart[ob])     = o0;
    *reinterpret_cast<bf16x8*>(&hpart[ob + 8]) = o1;
    sdtb[(size_t)(b * CK + c) * DI + d] = sdt;
}

// -------- scan pass B: chunk combine, hpart -> hentry (bf16), batched --------
__global__ __launch_bounds__(256) void scan_combine(
    const float* __restrict__ A_log, const float* __restrict__ sdtb,
    const __bf16* __restrict__ hpart, __bf16* __restrict__ hentry)
{
    const int idx = blockIdx.x * 256 + threadIdx.x;
    const int n = idx & 15;
    const int d = (idx >> 4) & (DI - 1);
    const int b = idx >> 15;
    const float A = -__expf(A_log[(size_t)d * 16 + n]);
    float h = 0.f;
    for (int cb = 0; cb < CK / 16; cb++) {
        float hl[16], sv[16];
        #pragma unroll
        for (int j = 0; j < 16; j++) {
            const int c = cb * 16 + j;
            hl[j] = (float)hpart[((size_t)(b * CK + c) * DI + d) * 16 + n];
            sv[j] = sdtb[(size_t)(b * CK + c) * DI + d];
        }
        #pragma unroll
        for (int j = 0; j < 16; j++) {
            const int c = cb * 16 + j;
            hentry[((size_t)(b * CK + c) * DI + d) * 16 + n] = (__bf16)h;
            h = __expf(A * sv[j]) * h + hl[j];
        }
    }
}

// -------- scan pass C: seeded re-scan, emit y (D-skip + z-gate) as bf16 ------
__global__ __launch_bounds__(256) void scan_final(
    const __bf16* __restrict__ xzb, const __bf16* __restrict__ xcb,
    const float* __restrict__ xdbl, const __bf16* __restrict__ dtb,
    const float* __restrict__ A_log, const float* __restrict__ Dp,
    const __bf16* __restrict__ hentry, __bf16* __restrict__ yb)
{
    __shared__ float Bsh[CL][16];
    __shared__ float Csh[CL][16];
    const int tid = threadIdx.x;
    const int d = blockIdx.x * 256 + tid;
    const int c = blockIdx.y, b = blockIdx.z;
    const size_t base = (size_t)b * SEQL + c * CL;
    {
        const int st = tid >> 4, sg = tid & 15;
        if (st < CL)
            Bsh[st][sg] = xdbl[(base + st) * XNP + DTR + sg];
        else if (st < 2 * CL)
            Csh[st - CL][sg] = xdbl[(base + st - CL) * XNP + DTR + DS + sg];
    }
    float dtv[CL], xcv[CL], zv[CL];
    #pragma unroll
    for (int t = 0; t < CL; t++) {
        dtv[t] = (float)dtb[(base + t) * DI + d];
        xcv[t] = (float)xcb[(base + t) * DI + d];
        zv[t]  = (float)xzb[(base + t) * (2 * DI) + DI + d];
    }
    float Av[16];
    #pragma unroll
    for (int i = 0; i < 4; i++) {
        const float4 v = *reinterpret_cast<const float4*>(&A_log[(size_t)d * 16 + i * 4]);
        Av[i*4+0] = -__expf(v.x); Av[i*4+1] = -__expf(v.y);
        Av[i*4+2] = -__expf(v.z); Av[i*4+3] = -__expf(v.w);
    }
    float h[16];
    const size_t ob = ((size_t)(b * CK + c) * DI + d) * 16;
    {
        const bf16x8 v0 = *reinterpret_cast<const bf16x8*>(&hentry[ob]);
        const bf16x8 v1 = *reinterpret_cast<const bf16x8*>(&hentry[ob + 8]);
        #pragma unroll
        for (int i = 0; i < 8; i++) { h[i] = (float)v0[i]; h[i + 8] = (float)v1[i]; }
    }
    const float Dv = Dp[d];
    __syncthreads();
    #pragma unroll
    for (int t = 0; t < CL; t++) {
        const float dx = dtv[t] * xcv[t];
        float y = 0.f;
        #pragma unroll
        for (int n = 0; n < 16; n++) {
            h[n] = __expf(dtv[t] * Av[n]) * h[n] + dx * Bsh[t][n];
            y += h[n] * Csh[t][n];
        }
        y += xcv[t] * Dv;
        y *= zv[t] / (1.f + __expf(-zv[t]));
        yb[(base + t) * DI + d] = (__bf16)y;
    }
}

// -------- out = x + LayerNorm(sum of 4 bf16 partials) ------------------------
__global__ __launch_bounds__(256) void ln_add(
    const float* __restrict__ x, const __bf16* __restrict__ mpart,
    const float* __restrict__ gamma, const float* __restrict__ beta,
    float* __restrict__ out)
{
    const int tok = blockIdx.x;
    const int tid = threadIdx.x;
    const int lane = tid & 63, wave = tid >> 6;
    __shared__ float red[4];
    __shared__ float stats[2];

    float4 v = {0.f, 0.f, 0.f, 0.f};
    #pragma unroll
    for (int p = 0; p < 4; p++) {
        const bf16x4 mv = *reinterpret_cast<const bf16x4*>(
            &mpart[((size_t)p * NTOK + tok) * DM + tid * 4]);
        v.x += (float)mv[0]; v.y += (float)mv[1];
        v.z += (float)mv[2]; v.w += (float)mv[3];
    }
    float s = v.x + v.y + v.z + v.w;
    #pragma unroll
    for (int o = 32; o > 0; o >>= 1) s += __shfl_down(s, o, 64);
    if (lane == 0) red[wave] = s;
    __syncthreads();
    if (tid == 0) stats[0] = (red[0] + red[1] + red[2] + red[3]) * (1.f / DM);
    __syncthreads();
    const float mu = stats[0];
    const float dx = v.x - mu, dy = v.y - mu, dz = v.z - mu, dw = v.w - mu;
    float q = dx * dx + dy * dy + dz * dz + dw * dw;
    #pragma unroll
    for (int o = 32; o > 0; o >>= 1) q += __shfl_down(q, o, 64);
    if (lane == 0) red[wave] = q;
    __syncthreads();
    if (tid == 0)
        stats[1] = rsqrtf((red[0] + red[1] + red[2] + red[3]) * (1.f / DM) + 1e-6f);
    __syncthreads();
    const float rs = stats[1];

    const float4 g  = reinterpret_cast<const float4*>(gamma)[tid];
    const float4 bb = reinterpret_cast<const float4*>(beta)[tid];
    const float4 xv = reinterpret_cast<const float4*>(&x[(size_t)tok * DM])[tid];
    float4 o;
    o.x = xv.x + dx * rs * g.x + bb.x;
    o.y = xv.y + dy * rs * g.y + bb.y;
    o.z = xv.z + dz * rs * g.z + bb.z;
    o.w = xv.w + dw * rs * g.w + bb.w;
    reinterpret_cast<float4*>(&out[(size_t)tok * DM])[tid] = o;
}

extern "C" void kernel_launch(void* const* d_in, const int* in_sizes, int n_in,
                              void* d_out, int out_size, void* d_ws, size_t ws_size,
                              hipStream_t stream)
{
    const float* x      = (const float*)d_in[0];
    const float* W_in   = (const float*)d_in[1];
    const float* conv_w = (const float*)d_in[2];
    const float* conv_b = (const float*)d_in[3];
    const float* W_xprj = (const float*)d_in[4];
    const float* W_dt   = (const float*)d_in[5];
    const float* b_dt   = (const float*)d_in[6];
    const float* A_log  = (const float*)d_in[7];
    const float* D_par  = (const float*)d_in[8];
    const float* W_out  = (const float*)d_in[9];
    const float* gamma  = (const float*)d_in[10];
    const float* beta   = (const float*)d_in[11];
    float* out = (float*)d_out;

    // workspace layout (byte offsets, non-aliasing, ~113 MB)
    char* w = (char*)d_ws;
    __bf16* xzb    = (__bf16*)(w + 0);          // 16 MB [NTOK][4096] (xi|z)
    __bf16* xcb    = (__bf16*)(w + 16777216);   //  8 MB [NTOK][DI]
    float*  xdbl   = (float*) (w + 25165824);   //  1 MB [NTOK][128]
    __bf16* dtb    = (__bf16*)(w + 26214400);   //  8 MB [NTOK][DI]
    __bf16* mpart  = (__bf16*)(w + 34603008);   // 16 MB [4][NTOK][DM]
    __bf16* hpart  = (__bf16*)(w + 51380224);   // 16 MB [NB*CK][DI][16]
    __bf16* hentry = (__bf16*)(w + 68157440);   // 16 MB [NB*CK][DI][16]
    float*  sdtb   = (float*) (w + 84934656);   //  2 MB [NB*CK][DI]
    __bf16* xb     = (__bf16*)(w + 87031808);   //  4 MB [NTOK][DM]
    __bf16* W_inT  = (__bf16*)(w + 91226112);   //  8 MB [4096][DM]
    __bf16* W_outT = (__bf16*)(w + 99614720);   //  4 MB [DM][DI]
    __bf16* W_xprT = (__bf16*)(w + 103809024);  // .5 MB [128][DI]
    __bf16* WdtT   = (__bf16*)(w + 104333312);  // .25MB [DI][64]
    __bf16* yb     = (__bf16*)(w + 104595456);  //  8 MB [NTOK][DI]

    // 0. fused prep
    prep<<<PREP_BLOCKS, 256, 0, stream>>>(
        x, W_in, W_out, W_dt, W_xprj, xb, W_inT, W_outT, WdtT, W_xprT, xdbl);

    // 1. xz = x @ W_in  (M=2048, N=4096, K=1024) -> bf16, TN=64 -> 1024 blocks
    gemm_bf16<3, 2, 64><<<dim3(64, 16, 1), 256, 0, stream>>>(
        xb, W_inT, xzb, NTOK, 2 * DI, DM, 2 * DI, nullptr);

    // 2. conv + silu -> bf16
    conv_silu<<<(NTOK * DI / 8) / 256, 256, 0, stream>>>(xzb, conv_w, conv_b, xcb);

    // 3. x_dbl = xc @ W_xproj  (N=128 pad, K=2048), split-K=16, atomic f32
    gemm_bf16<1, 0, 128><<<dim3(1, 16, 16), 256, 0, stream>>>(
        xcb, W_xprT, xdbl, NTOK, XNP, DI, XNP, nullptr);

    // 4. dt = softplus(dt_r @ W_dt + b_dt) -> bf16, TN=64 -> 512 blocks
    gemm_bf16<2, 0, 64><<<dim3(32, 16, 1), 256, 0, stream>>>(
        (const __bf16*)xdbl, WdtT, dtb, NTOK, DI, DTR, DI, b_dt);

    // 5. chunked selective scan (CK=128 chunks of CL=8 -> 2048 blocks A/C)
    scan_partial<<<dim3(DI / 256, CK, NB), 256, 0, stream>>>(
        xcb, xdbl, dtb, A_log, hpart, sdtb);
    scan_combine<<<NB * DI * DS / 256, 256, 0, stream>>>(A_log, sdtb, hpart, hentry);
    scan_final<<<dim3(DI / 256, CK, NB), 256, 0, stream>>>(
        xzb, xcb, xdbl, dtb, A_log, D_par, hentry, yb);

    // 6. m partials = y @ W_out  (split-K=4, TN=64 -> 1024 blocks, bf16 partials)
    gemm_bf16<3, 1, 64><<<dim3(16, 16, 4), 256, 0, stream>>>(
        yb, W_outT, mpart, NTOK, DM, DI, DM, nullptr);

    // 7. out = x + LN(sum of partials)
    ln_add<<<NTOK, 256, 0, stream>>>(x, mpart, gamma, beta, out);
}

// Round 15
// 158.441 us; speedup vs baseline: 1.0275x; 1.0274x over previous
//
#include <hip/hip_runtime.h>
#include <math.h>

#define DM   1024
#define DI   2048
#define DS   16
#define DTR  64
#define NB   2
#define SEQL 1024
#define NTOK (NB*SEQL)
#define XND  96   /* DTR + 2*DS */
#define XNP  128  /* padded xproj width */
#define CK   128  /* scan chunks */
#define CL   8    /* chunk length */

typedef __bf16 bf16x8 __attribute__((ext_vector_type(8)));
typedef __bf16 bf16x4 __attribute__((ext_vector_type(4)));
typedef float  f32x4  __attribute__((ext_vector_type(4)));

// ------------- fused prep: zeroing + conversions + transposes ----------------
#define PREP_BLOCKS 3872

__device__ inline void trans_tile64(const float* __restrict__ W,
                                    __bf16* __restrict__ WT, int K, int N,
                                    int n0, int k0, int tid, __bf16 (*t)[65])
{
    const int tx = tid & 63, ty = tid >> 6;   // ty 0..3
    #pragma unroll
    for (int i = 0; i < 16; i++)
        t[ty * 16 + i][tx] = (__bf16)W[(size_t)(k0 + ty * 16 + i) * N + n0 + tx];
    __syncthreads();
    #pragma unroll
    for (int i = 0; i < 16; i++)
        WT[(size_t)(n0 + ty * 16 + i) * K + k0 + tx] = t[tx][ty * 16 + i];
}

__global__ __launch_bounds__(256) void prep(
    const float* __restrict__ x, const float* __restrict__ W_in,
    const float* __restrict__ W_out, const float* __restrict__ W_dt,
    const float* __restrict__ W_xprj,
    __bf16* __restrict__ xb, __bf16* __restrict__ W_inT,
    __bf16* __restrict__ W_outT, __bf16* __restrict__ WdtT,
    __bf16* __restrict__ W_xprT, float* __restrict__ xdbl)
{
    __shared__ __bf16 t[64][65];
    int bid = blockIdx.x;
    const int tid = threadIdx.x;

    if (bid < 256) {                        // R0: zero xdbl
        const int i = bid * 1024 + tid * 4;
        const float4 z = {0.f, 0.f, 0.f, 0.f};
        *reinterpret_cast<float4*>(&xdbl[i]) = z;
        return;
    }
    bid -= 256;
    if (bid < 1024) {                       // R1: cvt x -> xb
        const int e = (bid * 256 + tid) * 8;
        const float4 v0 = *reinterpret_cast<const float4*>(&x[e]);
        const float4 v1 = *reinterpret_cast<const float4*>(&x[e + 4]);
        bf16x8 o;
        o[0] = (__bf16)v0.x; o[1] = (__bf16)v0.y; o[2] = (__bf16)v0.z; o[3] = (__bf16)v0.w;
        o[4] = (__bf16)v1.x; o[5] = (__bf16)v1.y; o[6] = (__bf16)v1.z; o[7] = (__bf16)v1.w;
        *reinterpret_cast<bf16x8*>(&xb[e]) = o;
        return;
    }
    bid -= 1024;
    if (bid < 1024) {                       // R2: W_in [1024][4096] -> T
        trans_tile64(W_in, W_inT, DM, 2 * DI, (bid & 63) * 64, (bid >> 6) * 64, tid, t);
        return;
    }
    bid -= 1024;
    if (bid < 512) {                        // R3: W_out [2048][1024] -> T
        trans_tile64(W_out, W_outT, DI, DM, (bid & 15) * 64, (bid >> 4) * 64, tid, t);
        return;
    }
    bid -= 512;
    if (bid < 32) {                         // R4: W_dt [64][2048] -> T
        trans_tile64(W_dt, WdtT, DTR, DI, bid * 64, 0, tid, t);
        return;
    }
    bid -= 32;
    {                                       // R5: xproj transpose+pad
        const int idx = bid * 256 + tid;
        const int k = idx & (DI - 1);
        const int n = idx >> 11;
        W_xprT[(size_t)n * DI + k] = (n < XND) ? (__bf16)W_xprj[(size_t)k * XND + n]
                                               : (__bf16)0.f;
    }
}

// -------- bf16 MFMA GEMM, 128xTN tile, BK=64, XOR-swizzled LDS ---------------
// PIPE path (MODE 1/3): double-buffered with COUNTED vmcnt + raw s_barrier
// (m201/T4 discipline) — next tile's global_load_lds stay in flight across
// the barrier; only current tile's LOADS are awaited. MODE 2 (reg-staged
// ds_write A): classic 2-barrier loop (nt==1 for dt anyway).
// MODE 1: atomicAdd f32 | 2: softplus(acc+bias)->bf16 LDS-bounce |
// 3: bf16 LDS-bounce (per-z partial offset when gridDim.z>1).
// SWZ 0: none | 1: XCD swizzle row-major | 2: XCD swizzle col-major.
template<int MODE, int SWZ, int TN>
__global__ __launch_bounds__(256) void gemm_bf16(
    const __bf16* __restrict__ A, const __bf16* __restrict__ Bt,
    void* __restrict__ Cp, int M, int N, int K, int ldc,
    const float* __restrict__ bias)
{
    constexpr int NFR = TN / 32;            // n-fragments per wave per ks
    constexpr bool PIPE = (MODE != 2);
    constexpr int ASZ = 128 * 64, BSZ = TN * 64;
    constexpr int STG = (PIPE ? 2 : 1) * (ASZ + BSZ);
    constexpr int SMEM = (STG > 128 * TN) ? STG : 128 * TN;
    __shared__ __bf16 smem[SMEM];
    const int tid  = threadIdx.x;
    const int lane = tid & 63;
    const int wid  = tid >> 6;
    const int wr   = wid >> 1, wc = wid & 1;

    int bx = blockIdx.x, by = blockIdx.y;
    if (SWZ != 0) {
        const int gx = gridDim.x, gy = gridDim.y;
        const int nxy = gx * gy;            // multiple of 8
        const int q = nxy >> 3;
        int lin = by * gx + bx;
        lin = (lin & 7) * q + (lin >> 3);
        if (SWZ == 1) { by = lin / gx; bx = lin % gx; }
        else          { bx = lin / gy; by = lin % gy; }
    }
    const int brow = by * 128, bcol = bx * TN;
    const int kper = K / gridDim.z;
    const int kbeg = blockIdx.z * kper, kend = kbeg + kper;

    f32x4 acc[4][NFR] = {};

    auto stage = [&](int buf, int k0) {
        __bf16* As = smem + buf * (ASZ + BSZ);
        __bf16* Bs = As + ASZ;
        if (MODE == 2) {
            const float* Af = reinterpret_cast<const float*>(A);
            #pragma unroll
            for (int p = 0; p < 4; p++) {
                const int i = p * 256 + tid;
                const int r = i >> 3;
                const int j = i & 7;
                const float4 v0 = *reinterpret_cast<const float4*>(
                    &Af[(size_t)(brow + r) * XNP + j * 8]);
                const float4 v1 = *reinterpret_cast<const float4*>(
                    &Af[(size_t)(brow + r) * XNP + j * 8 + 4]);
                bf16x8 o;
                o[0] = (__bf16)v0.x; o[1] = (__bf16)v0.y; o[2] = (__bf16)v0.z; o[3] = (__bf16)v0.w;
                o[4] = (__bf16)v1.x; o[5] = (__bf16)v1.y; o[6] = (__bf16)v1.z; o[7] = (__bf16)v1.w;
                *reinterpret_cast<bf16x8*>(&As[r * 64 + ((j ^ (r & 7))) * 8]) = o;
            }
        } else {
            #pragma unroll
            for (int p = 0; p < 4; p++) {
                const int i = p * 256 + tid;
                const int r = i >> 3;
                const int gc = ((i & 7) ^ (r & 7)) * 8;
                __builtin_amdgcn_global_load_lds(
                    (const __attribute__((address_space(1))) void*)(A + (size_t)(brow + r) * K + k0 + gc),
                    (__attribute__((address_space(3))) void*)(&As[i * 8]), 16, 0, 0);
            }
        }
        #pragma unroll
        for (int p = 0; p < TN / 32; p++) {
            const int i = p * 256 + tid;
            const int r = i >> 3;
            const int gc = ((i & 7) ^ (r & 7)) * 8;
            __builtin_amdgcn_global_load_lds(
                (const __attribute__((address_space(1))) void*)(Bt + (size_t)(bcol + r) * K + k0 + gc),
                (__attribute__((address_space(3))) void*)(&Bs[i * 8]), 16, 0, 0);
        }
    };

    auto compute = [&](int buf) {
        const __bf16* As = smem + buf * (ASZ + BSZ);
        const __bf16* Bs = As + ASZ;
        bf16x8 a[2][4], b[2][NFR];
        const int rA = wr * 64 + (lane & 15);
        const int rB = wc * (TN / 2) + (lane & 15);
        const int cq = lane >> 4;
        const int rx = lane & 7;
        #pragma unroll
        for (int ks = 0; ks < 2; ks++) {
            const int sl = ((ks * 4 + cq) ^ rx) * 8;
            #pragma unroll
            for (int m = 0; m < 4; m++)
                a[ks][m] = *reinterpret_cast<const bf16x8*>(&As[(rA + m * 16) * 64 + sl]);
            #pragma unroll
            for (int n = 0; n < NFR; n++)
                b[ks][n] = *reinterpret_cast<const bf16x8*>(&Bs[(rB + n * 16) * 64 + sl]);
        }
        #pragma unroll
        for (int ks = 0; ks < 2; ks++)
            #pragma unroll
            for (int m = 0; m < 4; m++)
                #pragma unroll
                for (int n = 0; n < NFR; n++)
                    acc[m][n] = __builtin_amdgcn_mfma_f32_16x16x32_bf16(
                        a[ks][m], b[ks][n], acc[m][n], 0, 0, 0);
    };

    const int nt = (kend - kbeg) >> 6;
    if constexpr (PIPE) {
        constexpr int LOADS = 4 + TN / 32;   // per-thread gload_lds per stage
        stage(0, kbeg);
        int cur = 0;
        for (int t = 0; t < nt; t++) {
            if (t + 1 < nt) {
                stage(cur ^ 1, kbeg + ((t + 1) << 6));
                asm volatile("s_waitcnt vmcnt(%0)" :: "n"(LOADS) : "memory");
            } else {
                asm volatile("s_waitcnt vmcnt(0)" ::: "memory");
            }
            __builtin_amdgcn_s_barrier();          // cur's tile ready for all
            __builtin_amdgcn_sched_barrier(0);
            compute(cur);
            __builtin_amdgcn_sched_barrier(0);
            __builtin_amdgcn_s_barrier();          // all done reading cur
            cur ^= 1;
        }
    } else {
        for (int k0 = kbeg; k0 < kend; k0 += 64) {
            __syncthreads();
            stage(0, k0);
            __syncthreads();
            compute(0);
        }
    }

    const int crl = wr * 64 + (lane >> 4) * 4;   // local row base
    const int ccl = wc * (TN / 2) + (lane & 15); // local col base

    if (MODE == 1) {
        #pragma unroll
        for (int m = 0; m < 4; m++)
            #pragma unroll
            for (int n = 0; n < NFR; n++) {
                const int col = bcol + ccl + n * 16;
                #pragma unroll
                for (int j = 0; j < 4; j++)
                    atomicAdd(&((float*)Cp)[(size_t)(brow + crl + m * 16 + j) * ldc + col],
                              acc[m][n][j]);
            }
    } else {
        // ---- LDS-bounce epilogue: fragment -> LDS -> coalesced bf16x8 ----
        __syncthreads();
        __bf16* Cs = smem;
        #pragma unroll
        for (int m = 0; m < 4; m++)
            #pragma unroll
            for (int n = 0; n < NFR; n++) {
                #pragma unroll
                for (int j = 0; j < 4; j++) {
                    float v = acc[m][n][j];
                    if (MODE == 2) {
                        v += bias[bcol + ccl + n * 16];
                        v = fmaxf(v, 0.f) + log1pf(__expf(-fabsf(v)));
                    }
                    Cs[(crl + m * 16 + j) * TN + ccl + n * 16] = (__bf16)v;
                }
            }
        __syncthreads();
        __bf16* Cb = (__bf16*)Cp +
            (size_t)blockIdx.z * ((MODE == 3) ? (size_t)M * ldc : 0);
        constexpr int CHUNKS = 128 * TN / 8;
        #pragma unroll
        for (int p = 0; p < CHUNKS / 256; p++) {
            const int i = p * 256 + tid;
            const int r = i / (TN / 8);
            const int cc = (i % (TN / 8)) * 8;
            *reinterpret_cast<bf16x8*>(&Cb[(size_t)(brow + r) * ldc + bcol + cc]) =
                *reinterpret_cast<const bf16x8*>(&Cs[r * TN + cc]);
        }
    }
}

// -------- depthwise causal conv (k=4) + bias + SiLU, 8 ch/thread -------------
__global__ __launch_bounds__(256) void conv_silu(
    const __bf16* __restrict__ xzb, const float* __restrict__ conv_w,
    const float* __restrict__ conv_b, __bf16* __restrict__ xcb)
{
    const int g  = blockIdx.x * 256 + threadIdx.x;
    const int d0 = (g & 255) * 8;
    const int tok = g >> 8;
    const int t   = tok & (SEQL - 1);

    float4 wv[8];
    #pragma unroll
    for (int j = 0; j < 8; j++)
        wv[j] = *reinterpret_cast<const float4*>(&conv_w[(d0 + j) * 4]);
    float acc[8];
    {
        const float4 b0 = *reinterpret_cast<const float4*>(&conv_b[d0]);
        const float4 b1 = *reinterpret_cast<const float4*>(&conv_b[d0 + 4]);
        acc[0] = b0.x; acc[1] = b0.y; acc[2] = b0.z; acc[3] = b0.w;
        acc[4] = b1.x; acc[5] = b1.y; acc[6] = b1.z; acc[7] = b1.w;
    }
    #pragma unroll
    for (int k = 0; k < 4; k++) {
        const int tt = t + k - 3;
        if (tt >= 0) {
            const bf16x8 v = *reinterpret_cast<const bf16x8*>(
                &xzb[(size_t)(tok + k - 3) * (2 * DI) + d0]);
            #pragma unroll
            for (int j = 0; j < 8; j++) {
                const float wk = (k == 0) ? wv[j].x : (k == 1) ? wv[j].y
                               : (k == 2) ? wv[j].z : wv[j].w;
                acc[j] += (float)v[j] * wk;
            }
        }
    }
    bf16x8 o;
    #pragma unroll
    for (int j = 0; j < 8; j++) {
        const float a = acc[j];
        o[j] = (__bf16)(a / (1.f + __expf(-a)));
    }
    *reinterpret_cast<bf16x8*>(&xcb[(size_t)g * 8]) = o;
}

// -------- scan pass A: per-chunk local scan from h=0, bf16 h out -------------
__global__ __launch_bounds__(256) void scan_partial(
    const __bf16* __restrict__ xcb, const float* __restrict__ xdbl,
    const __bf16* __restrict__ dtb, const float* __restrict__ A_log,
    __bf16* __restrict__ hpart, float* __restrict__ sdtb)
{
    __shared__ float Bsh[CL][16];
    const int tid = threadIdx.x;
    const int d = blockIdx.x * 256 + tid;
    const int c = blockIdx.y, b = blockIdx.z;
    const size_t base = (size_t)b * SEQL + c * CL;
    {
        const int st = tid >> 4, sg = tid & 15;
        if (st < CL) Bsh[st][sg] = xdbl[(base + st) * XNP + DTR + sg];
    }
    float dtv[CL], xcv[CL];
    #pragma unroll
    for (int t = 0; t < CL; t++) {
        dtv[t] = (float)dtb[(base + t) * DI + d];
        xcv[t] = (float)xcb[(base + t) * DI + d];
    }
    float Av[16];
    #pragma unroll
    for (int i = 0; i < 4; i++) {
        const float4 v = *reinterpret_cast<const float4*>(&A_log[(size_t)d * 16 + i * 4]);
        Av[i*4+0] = -__expf(v.x); Av[i*4+1] = -__expf(v.y);
        Av[i*4+2] = -__expf(v.z); Av[i*4+3] = -__expf(v.w);
    }
    __syncthreads();
    float h[16] = {};
    float sdt = 0.f;
    #pragma unroll
    for (int t = 0; t < CL; t++) {
        sdt += dtv[t];
        const float dx = dtv[t] * xcv[t];
        #pragma unroll
        for (int n = 0; n < 16; n++)
            h[n] = __expf(dtv[t] * Av[n]) * h[n] + dx * Bsh[t][n];
    }
    const size_t ob = ((size_t)(b * CK + c) * DI + d) * 16;
    bf16x8 o0, o1;
    #pragma unroll
    for (int i = 0; i < 8; i++) { o0[i] = (__bf16)h[i]; o1[i] = (__bf16)h[i + 8]; }
    *reinterpret_cast<bf16x8*>(&hpart[ob])     = o0;
    *reinterpret_cast<bf16x8*>(&hpart[ob + 8]) = o1;
    sdtb[(size_t)(b * CK + c) * DI + d] = sdt;
}

// -------- scan pass B: chunk combine, hpart -> hentry (bf16), batched --------
__global__ __launch_bounds__(256) void scan_combine(
    const float* __restrict__ A_log, const float* __restrict__ sdtb,
    const __bf16* __restrict__ hpart, __bf16* __restrict__ hentry)
{
    const int idx = blockIdx.x * 256 + threadIdx.x;
    const int n = idx & 15;
    const int d = (idx >> 4) & (DI - 1);
    const int b = idx >> 15;
    const float A = -__expf(A_log[(size_t)d * 16 + n]);
    float h = 0.f;
    for (int cb = 0; cb < CK / 16; cb++) {
        float hl[16], sv[16];
        #pragma unroll
        for (int j = 0; j < 16; j++) {
            const int c = cb * 16 + j;
            hl[j] = (float)hpart[((size_t)(b * CK + c) * DI + d) * 16 + n];
            sv[j] = sdtb[(size_t)(b * CK + c) * DI + d];
        }
        #pragma unroll
        for (int j = 0; j < 16; j++) {
            const int c = cb * 16 + j;
            hentry[((size_t)(b * CK + c) * DI + d) * 16 + n] = (__bf16)h;
            h = __expf(A * sv[j]) * h + hl[j];
        }
    }
}

// -------- scan pass C: seeded re-scan, emit y (D-skip + z-gate) as bf16 ------
__global__ __launch_bounds__(256) void scan_final(
    const __bf16* __restrict__ xzb, const __bf16* __restrict__ xcb,
    const float* __restrict__ xdbl, const __bf16* __restrict__ dtb,
    const float* __restrict__ A_log, const float* __restrict__ Dp,
    const __bf16* __restrict__ hentry, __bf16* __restrict__ yb)
{
    __shared__ float Bsh[CL][16];
    __shared__ float Csh[CL][16];
    const int tid = threadIdx.x;
    const int d = blockIdx.x * 256 + tid;
    const int c = blockIdx.y, b = blockIdx.z;
    const size_t base = (size_t)b * SEQL + c * CL;
    {
        const int st = tid >> 4, sg = tid & 15;
        if (st < CL)
            Bsh[st][sg] = xdbl[(base + st) * XNP + DTR + sg];
        else if (st < 2 * CL)
            Csh[st - CL][sg] = xdbl[(base + st - CL) * XNP + DTR + DS + sg];
    }
    float dtv[CL], xcv[CL], zv[CL];
    #pragma unroll
    for (int t = 0; t < CL; t++) {
        dtv[t] = (float)dtb[(base + t) * DI + d];
        xcv[t] = (float)xcb[(base + t) * DI + d];
        zv[t]  = (float)xzb[(base + t) * (2 * DI) + DI + d];
    }
    float Av[16];
    #pragma unroll
    for (int i = 0; i < 4; i++) {
        const float4 v = *reinterpret_cast<const float4*>(&A_log[(size_t)d * 16 + i * 4]);
        Av[i*4+0] = -__expf(v.x); Av[i*4+1] = -__expf(v.y);
        Av[i*4+2] = -__expf(v.z); Av[i*4+3] = -__expf(v.w);
    }
    float h[16];
    const size_t ob = ((size_t)(b * CK + c) * DI + d) * 16;
    {
        const bf16x8 v0 = *reinterpret_cast<const bf16x8*>(&hentry[ob]);
        const bf16x8 v1 = *reinterpret_cast<const bf16x8*>(&hentry[ob + 8]);
        #pragma unroll
        for (int i = 0; i < 8; i++) { h[i] = (float)v0[i]; h[i + 8] = (float)v1[i]; }
    }
    const float Dv = Dp[d];
    __syncthreads();
    #pragma unroll
    for (int t = 0; t < CL; t++) {
        const float dx = dtv[t] * xcv[t];
        float y = 0.f;
        #pragma unroll
        for (int n = 0; n < 16; n++) {
            h[n] = __expf(dtv[t] * Av[n]) * h[n] + dx * Bsh[t][n];
            y += h[n] * Csh[t][n];
        }
        y += xcv[t] * Dv;
        y *= zv[t] / (1.f + __expf(-zv[t]));
        yb[(base + t) * DI + d] = (__bf16)y;
    }
}

// -------- out = x + LayerNorm(sum of 4 bf16 partials) ------------------------
__global__ __launch_bounds__(256) void ln_add(
    const float* __restrict__ x, const __bf16* __restrict__ mpart,
    const float* __restrict__ gamma, const float* __restrict__ beta,
    float* __restrict__ out)
{
    const int tok = blockIdx.x;
    const int tid = threadIdx.x;
    const int lane = tid & 63, wave = tid >> 6;
    __shared__ float red[4];
    __shared__ float stats[2];

    float4 v = {0.f, 0.f, 0.f, 0.f};
    #pragma unroll
    for (int p = 0; p < 4; p++) {
        const bf16x4 mv = *reinterpret_cast<const bf16x4*>(
            &mpart[((size_t)p * NTOK + tok) * DM + tid * 4]);
        v.x += (float)mv[0]; v.y += (float)mv[1];
        v.z += (float)mv[2]; v.w += (float)mv[3];
    }
    float s = v.x + v.y + v.z + v.w;
    #pragma unroll
    for (int o = 32; o > 0; o >>= 1) s += __shfl_down(s, o, 64);
    if (lane == 0) red[wave] = s;
    __syncthreads();
    if (tid == 0) stats[0] = (red[0] + red[1] + red[2] + red[3]) * (1.f / DM);
    __syncthreads();
    const float mu = stats[0];
    const float dx = v.x - mu, dy = v.y - mu, dz = v.z - mu, dw = v.w - mu;
    float q = dx * dx + dy * dy + dz * dz + dw * dw;
    #pragma unroll
    for (int o = 32; o > 0; o >>= 1) q += __shfl_down(q, o, 64);
    if (lane == 0) red[wave] = q;
    __syncthreads();
    if (tid == 0)
        stats[1] = rsqrtf((red[0] + red[1] + red[2] + red[3]) * (1.f / DM) + 1e-6f);
    __syncthreads();
    const float rs = stats[1];

    const float4 g  = reinterpret_cast<const float4*>(gamma)[tid];
    const float4 bb = reinterpret_cast<const float4*>(beta)[tid];
    const float4 xv = reinterpret_cast<const float4*>(&x[(size_t)tok * DM])[tid];
    float4 o;
    o.x = xv.x + dx * rs * g.x + bb.x;
    o.y = xv.y + dy * rs * g.y + bb.y;
    o.z = xv.z + dz * rs * g.z + bb.z;
    o.w = xv.w + dw * rs * g.w + bb.w;
    reinterpret_cast<float4*>(&out[(size_t)tok * DM])[tid] = o;
}

extern "C" void kernel_launch(void* const* d_in, const int* in_sizes, int n_in,
                              void* d_out, int out_size, void* d_ws, size_t ws_size,
                              hipStream_t stream)
{
    const float* x      = (const float*)d_in[0];
    const float* W_in   = (const float*)d_in[1];
    const float* conv_w = (const float*)d_in[2];
    const float* conv_b = (const float*)d_in[3];
    const float* W_xprj = (const float*)d_in[4];
    const float* W_dt   = (const float*)d_in[5];
    const float* b_dt   = (const float*)d_in[6];
    const float* A_log  = (const float*)d_in[7];
    const float* D_par  = (const float*)d_in[8];
    const float* W_out  = (const float*)d_in[9];
    const float* gamma  = (const float*)d_in[10];
    const float* beta   = (const float*)d_in[11];
    float* out = (float*)d_out;

    // workspace layout (byte offsets, non-aliasing, ~113 MB)
    char* w = (char*)d_ws;
    __bf16* xzb    = (__bf16*)(w + 0);          // 16 MB [NTOK][4096] (xi|z)
    __bf16* xcb    = (__bf16*)(w + 16777216);   //  8 MB [NTOK][DI]
    float*  xdbl   = (float*) (w + 25165824);   //  1 MB [NTOK][128]
    __bf16* dtb    = (__bf16*)(w + 26214400);   //  8 MB [NTOK][DI]
    __bf16* mpart  = (__bf16*)(w + 34603008);   // 16 MB [4][NTOK][DM]
    __bf16* hpart  = (__bf16*)(w + 51380224);   // 16 MB [NB*CK][DI][16]
    __bf16* hentry = (__bf16*)(w + 68157440);   // 16 MB [NB*CK][DI][16]
    float*  sdtb   = (float*) (w + 84934656);   //  2 MB [NB*CK][DI]
    __bf16* xb     = (__bf16*)(w + 87031808);   //  4 MB [NTOK][DM]
    __bf16* W_inT  = (__bf16*)(w + 91226112);   //  8 MB [4096][DM]
    __bf16* W_outT = (__bf16*)(w + 99614720);   //  4 MB [DM][DI]
    __bf16* W_xprT = (__bf16*)(w + 103809024);  // .5 MB [128][DI]
    __bf16* WdtT   = (__bf16*)(w + 104333312);  // .25MB [DI][64]
    __bf16* yb     = (__bf16*)(w + 104595456);  //  8 MB [NTOK][DI]

    // 0. fused prep
    prep<<<PREP_BLOCKS, 256, 0, stream>>>(
        x, W_in, W_out, W_dt, W_xprj, xb, W_inT, W_outT, WdtT, W_xprT, xdbl);

    // 1. xz = x @ W_in  (M=2048, N=4096, K=1024) -> bf16, TN=64
    gemm_bf16<3, 2, 64><<<dim3(64, 16, 1), 256, 0, stream>>>(
        xb, W_inT, xzb, NTOK, 2 * DI, DM, 2 * DI, nullptr);

    // 2. conv + silu -> bf16
    conv_silu<<<(NTOK * DI / 8) / 256, 256, 0, stream>>>(xzb, conv_w, conv_b, xcb);

    // 3. x_dbl = xc @ W_xproj  (N=128 pad, K=2048), split-K=16, atomic f32
    gemm_bf16<1, 0, 128><<<dim3(1, 16, 16), 256, 0, stream>>>(
        xcb, W_xprT, xdbl, NTOK, XNP, DI, XNP, nullptr);

    // 4. dt = softplus(dt_r @ W_dt + b_dt) -> bf16, TN=64
    gemm_bf16<2, 0, 64><<<dim3(32, 16, 1), 256, 0, stream>>>(
        (const __bf16*)xdbl, WdtT, dtb, NTOK, DI, DTR, DI, b_dt);

    // 5. chunked selective scan (CK=128 chunks of CL=8 -> 2048 blocks A/C)
    scan_partial<<<dim3(DI / 256, CK, NB), 256, 0, stream>>>(
        xcb, xdbl, dtb, A_log, hpart, sdtb);
    scan_combine<<<NB * DI * DS / 256, 256, 0, stream>>>(A_log, sdtb, hpart, hentry);
    scan_final<<<dim3(DI / 256, CK, NB), 256, 0, stream>>>(
        xzb, xcb, xdbl, dtb, A_log, D_par, hentry, yb);

    // 6. m partials = y @ W_out  (split-K=4, TN=64, bf16 partials)
    gemm_bf16<3, 1, 64><<<dim3(16, 16, 4), 256, 0, stream>>>(
        yb, W_outT, mpart, NTOK, DM, DI, DM, nullptr);

    // 7. out = x + LN(sum of partials)
    ln_add<<<NTOK, 256, 0, stream>>>(x, mpart, gamma, beta, out);
}

// Round 16
// 155.265 us; speedup vs baseline: 1.0485x; 1.0205x over previous
//
#include <hip/hip_runtime.h>
#include <math.h>

#define DM   1024
#define DI   2048
#define DS   16
#define DTR  64
#define NB   2
#define SEQL 1024
#define NTOK (NB*SEQL)
#define XND  96   /* DTR + 2*DS */
#define XNP  128  /* padded xproj width */
#define CK   128  /* scan chunks */
#define CL   8    /* chunk length */

typedef __bf16 bf16x8 __attribute__((ext_vector_type(8)));
typedef __bf16 bf16x4 __attribute__((ext_vector_type(4)));
typedef float  f32x4  __attribute__((ext_vector_type(4)));

// ------------- fused prep: zeroing + conversions + transposes ----------------
#define PREP_BLOCKS 3872

__device__ inline void trans_tile64(const float* __restrict__ W,
                                    __bf16* __restrict__ WT, int K, int N,
                                    int n0, int k0, int tid, __bf16 (*t)[65])
{
    const int tx = tid & 63, ty = tid >> 6;   // ty 0..3
    #pragma unroll
    for (int i = 0; i < 16; i++)
        t[ty * 16 + i][tx] = (__bf16)W[(size_t)(k0 + ty * 16 + i) * N + n0 + tx];
    __syncthreads();
    #pragma unroll
    for (int i = 0; i < 16; i++)
        WT[(size_t)(n0 + ty * 16 + i) * K + k0 + tx] = t[tx][ty * 16 + i];
}

__global__ __launch_bounds__(256) void prep(
    const float* __restrict__ x, const float* __restrict__ W_in,
    const float* __restrict__ W_out, const float* __restrict__ W_dt,
    const float* __restrict__ W_xprj,
    __bf16* __restrict__ xb, __bf16* __restrict__ W_inT,
    __bf16* __restrict__ W_outT, __bf16* __restrict__ WdtT,
    __bf16* __restrict__ W_xprT, float* __restrict__ xdbl)
{
    __shared__ __bf16 t[64][65];
    int bid = blockIdx.x;
    const int tid = threadIdx.x;

    if (bid < 256) {                        // R0: zero xdbl
        const int i = bid * 1024 + tid * 4;
        const float4 z = {0.f, 0.f, 0.f, 0.f};
        *reinterpret_cast<float4*>(&xdbl[i]) = z;
        return;
    }
    bid -= 256;
    if (bid < 1024) {                       // R1: cvt x -> xb
        const int e = (bid * 256 + tid) * 8;
        const float4 v0 = *reinterpret_cast<const float4*>(&x[e]);
        const float4 v1 = *reinterpret_cast<const float4*>(&x[e + 4]);
        bf16x8 o;
        o[0] = (__bf16)v0.x; o[1] = (__bf16)v0.y; o[2] = (__bf16)v0.z; o[3] = (__bf16)v0.w;
        o[4] = (__bf16)v1.x; o[5] = (__bf16)v1.y; o[6] = (__bf16)v1.z; o[7] = (__bf16)v1.w;
        *reinterpret_cast<bf16x8*>(&xb[e]) = o;
        return;
    }
    bid -= 1024;
    if (bid < 1024) {                       // R2: W_in [1024][4096] -> T
        trans_tile64(W_in, W_inT, DM, 2 * DI, (bid & 63) * 64, (bid >> 6) * 64, tid, t);
        return;
    }
    bid -= 1024;
    if (bid < 512) {                        // R3: W_out [2048][1024] -> T
        trans_tile64(W_out, W_outT, DI, DM, (bid & 15) * 64, (bid >> 4) * 64, tid, t);
        return;
    }
    bid -= 512;
    if (bid < 32) {                         // R4: W_dt [64][2048] -> T
        trans_tile64(W_dt, WdtT, DTR, DI, bid * 64, 0, tid, t);
        return;
    }
    bid -= 32;
    {                                       // R5: xproj transpose+pad
        const int idx = bid * 256 + tid;
        const int k = idx & (DI - 1);
        const int n = idx >> 11;
        W_xprT[(size_t)n * DI + k] = (n < XND) ? (__bf16)W_xprj[(size_t)k * XND + n]
                                               : (__bf16)0.f;
    }
}

// -------- bf16 MFMA GEMM, 128xTN tile, BK=64, XOR-swizzled LDS ---------------
// PIPE path (MODE 1/3): double-buffered with COUNTED vmcnt + raw s_barrier
// (m201/T4 discipline). MODE 2: classic 2-barrier loop (nt==1 for dt).
// MODE 1: atomicAdd f32 | 2: softplus(acc+bias)->bf16 LDS-bounce |
// 3: bf16 LDS-bounce (per-z partial offset when gridDim.z>1).
// SWZ 0: none | 1: XCD swizzle row-major | 2: XCD swizzle col-major.
// TN=128 preferred when piped: 33% less LDS traffic per output than TN=64.
template<int MODE, int SWZ, int TN>
__global__ __launch_bounds__(256) void gemm_bf16(
    const __bf16* __restrict__ A, const __bf16* __restrict__ Bt,
    void* __restrict__ Cp, int M, int N, int K, int ldc,
    const float* __restrict__ bias)
{
    constexpr int NFR = TN / 32;            // n-fragments per wave per ks
    constexpr bool PIPE = (MODE != 2);
    constexpr int ASZ = 128 * 64, BSZ = TN * 64;
    constexpr int STG = (PIPE ? 2 : 1) * (ASZ + BSZ);
    constexpr int SMEM = (STG > 128 * TN) ? STG : 128 * TN;
    __shared__ __bf16 smem[SMEM];
    const int tid  = threadIdx.x;
    const int lane = tid & 63;
    const int wid  = tid >> 6;
    const int wr   = wid >> 1, wc = wid & 1;

    int bx = blockIdx.x, by = blockIdx.y;
    if (SWZ != 0) {
        const int gx = gridDim.x, gy = gridDim.y;
        const int nxy = gx * gy;            // multiple of 8
        const int q = nxy >> 3;
        int lin = by * gx + bx;
        lin = (lin & 7) * q + (lin >> 3);
        if (SWZ == 1) { by = lin / gx; bx = lin % gx; }
        else          { bx = lin / gy; by = lin % gy; }
    }
    const int brow = by * 128, bcol = bx * TN;
    const int kper = K / gridDim.z;
    const int kbeg = blockIdx.z * kper, kend = kbeg + kper;

    f32x4 acc[4][NFR] = {};

    auto stage = [&](int buf, int k0) {
        __bf16* As = smem + buf * (ASZ + BSZ);
        __bf16* Bs = As + ASZ;
        if (MODE == 2) {
            const float* Af = reinterpret_cast<const float*>(A);
            #pragma unroll
            for (int p = 0; p < 4; p++) {
                const int i = p * 256 + tid;
                const int r = i >> 3;
                const int j = i & 7;
                const float4 v0 = *reinterpret_cast<const float4*>(
                    &Af[(size_t)(brow + r) * XNP + j * 8]);
                const float4 v1 = *reinterpret_cast<const float4*>(
                    &Af[(size_t)(brow + r) * XNP + j * 8 + 4]);
                bf16x8 o;
                o[0] = (__bf16)v0.x; o[1] = (__bf16)v0.y; o[2] = (__bf16)v0.z; o[3] = (__bf16)v0.w;
                o[4] = (__bf16)v1.x; o[5] = (__bf16)v1.y; o[6] = (__bf16)v1.z; o[7] = (__bf16)v1.w;
                *reinterpret_cast<bf16x8*>(&As[r * 64 + ((j ^ (r & 7))) * 8]) = o;
            }
        } else {
            #pragma unroll
            for (int p = 0; p < 4; p++) {
                const int i = p * 256 + tid;
                const int r = i >> 3;
                const int gc = ((i & 7) ^ (r & 7)) * 8;
                __builtin_amdgcn_global_load_lds(
                    (const __attribute__((address_space(1))) void*)(A + (size_t)(brow + r) * K + k0 + gc),
                    (__attribute__((address_space(3))) void*)(&As[i * 8]), 16, 0, 0);
            }
        }
        #pragma unroll
        for (int p = 0; p < TN / 32; p++) {
            const int i = p * 256 + tid;
            const int r = i >> 3;
            const int gc = ((i & 7) ^ (r & 7)) * 8;
            __builtin_amdgcn_global_load_lds(
                (const __attribute__((address_space(1))) void*)(Bt + (size_t)(bcol + r) * K + k0 + gc),
                (__attribute__((address_space(3))) void*)(&Bs[i * 8]), 16, 0, 0);
        }
    };

    auto compute = [&](int buf) {
        const __bf16* As = smem + buf * (ASZ + BSZ);
        const __bf16* Bs = As + ASZ;
        bf16x8 a[2][4], b[2][NFR];
        const int rA = wr * 64 + (lane & 15);
        const int rB = wc * (TN / 2) + (lane & 15);
        const int cq = lane >> 4;
        const int rx = lane & 7;
        #pragma unroll
        for (int ks = 0; ks < 2; ks++) {
            const int sl = ((ks * 4 + cq) ^ rx) * 8;
            #pragma unroll
            for (int m = 0; m < 4; m++)
                a[ks][m] = *reinterpret_cast<const bf16x8*>(&As[(rA + m * 16) * 64 + sl]);
            #pragma unroll
            for (int n = 0; n < NFR; n++)
                b[ks][n] = *reinterpret_cast<const bf16x8*>(&Bs[(rB + n * 16) * 64 + sl]);
        }
        #pragma unroll
        for (int ks = 0; ks < 2; ks++)
            #pragma unroll
            for (int m = 0; m < 4; m++)
                #pragma unroll
                for (int n = 0; n < NFR; n++)
                    acc[m][n] = __builtin_amdgcn_mfma_f32_16x16x32_bf16(
                        a[ks][m], b[ks][n], acc[m][n], 0, 0, 0);
    };

    const int nt = (kend - kbeg) >> 6;
    if constexpr (PIPE) {
        constexpr int LOADS = 4 + TN / 32;   // per-thread gload_lds per stage
        stage(0, kbeg);
        int cur = 0;
        for (int t = 0; t < nt; t++) {
            if (t + 1 < nt) {
                stage(cur ^ 1, kbeg + ((t + 1) << 6));
                asm volatile("s_waitcnt vmcnt(%0)" :: "n"(LOADS) : "memory");
            } else {
                asm volatile("s_waitcnt vmcnt(0)" ::: "memory");
            }
            __builtin_amdgcn_s_barrier();          // cur's tile ready for all
            __builtin_amdgcn_sched_barrier(0);
            compute(cur);
            __builtin_amdgcn_sched_barrier(0);
            __builtin_amdgcn_s_barrier();          // all done reading cur
            cur ^= 1;
        }
    } else {
        for (int k0 = kbeg; k0 < kend; k0 += 64) {
            __syncthreads();
            stage(0, k0);
            __syncthreads();
            compute(0);
        }
    }

    const int crl = wr * 64 + (lane >> 4) * 4;   // local row base
    const int ccl = wc * (TN / 2) + (lane & 15); // local col base

    if (MODE == 1) {
        #pragma unroll
        for (int m = 0; m < 4; m++)
            #pragma unroll
            for (int n = 0; n < NFR; n++) {
                const int col = bcol + ccl + n * 16;
                #pragma unroll
                for (int j = 0; j < 4; j++)
                    atomicAdd(&((float*)Cp)[(size_t)(brow + crl + m * 16 + j) * ldc + col],
                              acc[m][n][j]);
            }
    } else {
        // ---- LDS-bounce epilogue: fragment -> LDS -> coalesced bf16x8 ----
        __syncthreads();
        __bf16* Cs = smem;
        #pragma unroll
        for (int m = 0; m < 4; m++)
            #pragma unroll
            for (int n = 0; n < NFR; n++) {
                #pragma unroll
                for (int j = 0; j < 4; j++) {
                    float v = acc[m][n][j];
                    if (MODE == 2) {
                        v += bias[bcol + ccl + n * 16];
                        v = fmaxf(v, 0.f) + log1pf(__expf(-fabsf(v)));
                    }
                    Cs[(crl + m * 16 + j) * TN + ccl + n * 16] = (__bf16)v;
                }
            }
        __syncthreads();
        __bf16* Cb = (__bf16*)Cp +
            (size_t)blockIdx.z * ((MODE == 3) ? (size_t)M * ldc : 0);
        constexpr int CHUNKS = 128 * TN / 8;
        #pragma unroll
        for (int p = 0; p < CHUNKS / 256; p++) {
            const int i = p * 256 + tid;
            const int r = i / (TN / 8);
            const int cc = (i % (TN / 8)) * 8;
            *reinterpret_cast<bf16x8*>(&Cb[(size_t)(brow + r) * ldc + bcol + cc]) =
                *reinterpret_cast<const bf16x8*>(&Cs[r * TN + cc]);
        }
    }
}

// -------- depthwise causal conv (k=4) + bias + SiLU, 8 ch/thread -------------
__global__ __launch_bounds__(256) void conv_silu(
    const __bf16* __restrict__ xzb, const float* __restrict__ conv_w,
    const float* __restrict__ conv_b, __bf16* __restrict__ xcb)
{
    const int g  = blockIdx.x * 256 + threadIdx.x;
    const int d0 = (g & 255) * 8;
    const int tok = g >> 8;
    const int t   = tok & (SEQL - 1);

    float4 wv[8];
    #pragma unroll
    for (int j = 0; j < 8; j++)
        wv[j] = *reinterpret_cast<const float4*>(&conv_w[(d0 + j) * 4]);
    float acc[8];
    {
        const float4 b0 = *reinterpret_cast<const float4*>(&conv_b[d0]);
        const float4 b1 = *reinterpret_cast<const float4*>(&conv_b[d0 + 4]);
        acc[0] = b0.x; acc[1] = b0.y; acc[2] = b0.z; acc[3] = b0.w;
        acc[4] = b1.x; acc[5] = b1.y; acc[6] = b1.z; acc[7] = b1.w;
    }
    #pragma unroll
    for (int k = 0; k < 4; k++) {
        const int tt = t + k - 3;
        if (tt >= 0) {
            const bf16x8 v = *reinterpret_cast<const bf16x8*>(
                &xzb[(size_t)(tok + k - 3) * (2 * DI) + d0]);
            #pragma unroll
            for (int j = 0; j < 8; j++) {
                const float wk = (k == 0) ? wv[j].x : (k == 1) ? wv[j].y
                               : (k == 2) ? wv[j].z : wv[j].w;
                acc[j] += (float)v[j] * wk;
            }
        }
    }
    bf16x8 o;
    #pragma unroll
    for (int j = 0; j < 8; j++) {
        const float a = acc[j];
        o[j] = (__bf16)(a / (1.f + __expf(-a)));
    }
    *reinterpret_cast<bf16x8*>(&xcb[(size_t)g * 8]) = o;
}

// -------- scan pass A: per-chunk local scan from h=0, bf16 h out -------------
__global__ __launch_bounds__(256) void scan_partial(
    const __bf16* __restrict__ xcb, const float* __restrict__ xdbl,
    const __bf16* __restrict__ dtb, const float* __restrict__ A_log,
    __bf16* __restrict__ hpart, float* __restrict__ sdtb)
{
    __shared__ float Bsh[CL][16];
    const int tid = threadIdx.x;
    const int d = blockIdx.x * 256 + tid;
    const int c = blockIdx.y, b = blockIdx.z;
    const size_t base = (size_t)b * SEQL + c * CL;
    {
        const int st = tid >> 4, sg = tid & 15;
        if (st < CL) Bsh[st][sg] = xdbl[(base + st) * XNP + DTR + sg];
    }
    float dtv[CL], xcv[CL];
    #pragma unroll
    for (int t = 0; t < CL; t++) {
        dtv[t] = (float)dtb[(base + t) * DI + d];
        xcv[t] = (float)xcb[(base + t) * DI + d];
    }
    float Av[16];
    #pragma unroll
    for (int i = 0; i < 4; i++) {
        const float4 v = *reinterpret_cast<const float4*>(&A_log[(size_t)d * 16 + i * 4]);
        Av[i*4+0] = -__expf(v.x); Av[i*4+1] = -__expf(v.y);
        Av[i*4+2] = -__expf(v.z); Av[i*4+3] = -__expf(v.w);
    }
    __syncthreads();
    float h[16] = {};
    float sdt = 0.f;
    #pragma unroll
    for (int t = 0; t < CL; t++) {
        sdt += dtv[t];
        const float dx = dtv[t] * xcv[t];
        #pragma unroll
        for (int n = 0; n < 16; n++)
            h[n] = __expf(dtv[t] * Av[n]) * h[n] + dx * Bsh[t][n];
    }
    const size_t ob = ((size_t)(b * CK + c) * DI + d) * 16;
    bf16x8 o0, o1;
    #pragma unroll
    for (int i = 0; i < 8; i++) { o0[i] = (__bf16)h[i]; o1[i] = (__bf16)h[i + 8]; }
    *reinterpret_cast<bf16x8*>(&hpart[ob])     = o0;
    *reinterpret_cast<bf16x8*>(&hpart[ob + 8]) = o1;
    sdtb[(size_t)(b * CK + c) * DI + d] = sdt;
}

// -------- scan pass B: chunk combine, hpart -> hentry (bf16), batched --------
__global__ __launch_bounds__(256) void scan_combine(
    const float* __restrict__ A_log, const float* __restrict__ sdtb,
    const __bf16* __restrict__ hpart, __bf16* __restrict__ hentry)
{
    const int idx = blockIdx.x * 256 + threadIdx.x;
    const int n = idx & 15;
    const int d = (idx >> 4) & (DI - 1);
    const int b = idx >> 15;
    const float A = -__expf(A_log[(size_t)d * 16 + n]);
    float h = 0.f;
    for (int cb = 0; cb < CK / 16; cb++) {
        float hl[16], sv[16];
        #pragma unroll
        for (int j = 0; j < 16; j++) {
            const int c = cb * 16 + j;
            hl[j] = (float)hpart[((size_t)(b * CK + c) * DI + d) * 16 + n];
            sv[j] = sdtb[(size_t)(b * CK + c) * DI + d];
        }
        #pragma unroll
        for (int j = 0; j < 16; j++) {
            const int c = cb * 16 + j;
            hentry[((size_t)(b * CK + c) * DI + d) * 16 + n] = (__bf16)h;
            h = __expf(A * sv[j]) * h + hl[j];
        }
    }
}

// -------- scan pass C: seeded re-scan, emit y (D-skip + z-gate) as bf16 ------
__global__ __launch_bounds__(256) void scan_final(
    const __bf16* __restrict__ xzb, const __bf16* __restrict__ xcb,
    const float* __restrict__ xdbl, const __bf16* __restrict__ dtb,
    const float* __restrict__ A_log, const float* __restrict__ Dp,
    const __bf16* __restrict__ hentry, __bf16* __restrict__ yb)
{
    __shared__ float Bsh[CL][16];
    __shared__ float Csh[CL][16];
    const int tid = threadIdx.x;
    const int d = blockIdx.x * 256 + tid;
    const int c = blockIdx.y, b = blockIdx.z;
    const size_t base = (size_t)b * SEQL + c * CL;
    {
        const int st = tid >> 4, sg = tid & 15;
        if (st < CL)
            Bsh[st][sg] = xdbl[(base + st) * XNP + DTR + sg];
        else if (st < 2 * CL)
            Csh[st - CL][sg] = xdbl[(base + st - CL) * XNP + DTR + DS + sg];
    }
    float dtv[CL], xcv[CL], zv[CL];
    #pragma unroll
    for (int t = 0; t < CL; t++) {
        dtv[t] = (float)dtb[(base + t) * DI + d];
        xcv[t] = (float)xcb[(base + t) * DI + d];
        zv[t]  = (float)xzb[(base + t) * (2 * DI) + DI + d];
    }
    float Av[16];
    #pragma unroll
    for (int i = 0; i < 4; i++) {
        const float4 v = *reinterpret_cast<const float4*>(&A_log[(size_t)d * 16 + i * 4]);
        Av[i*4+0] = -__expf(v.x); Av[i*4+1] = -__expf(v.y);
        Av[i*4+2] = -__expf(v.z); Av[i*4+3] = -__expf(v.w);
    }
    float h[16];
    const size_t ob = ((size_t)(b * CK + c) * DI + d) * 16;
    {
        const bf16x8 v0 = *reinterpret_cast<const bf16x8*>(&hentry[ob]);
        const bf16x8 v1 = *reinterpret_cast<const bf16x8*>(&hentry[ob + 8]);
        #pragma unroll
        for (int i = 0; i < 8; i++) { h[i] = (float)v0[i]; h[i + 8] = (float)v1[i]; }
    }
    const float Dv = Dp[d];
    __syncthreads();
    #pragma unroll
    for (int t = 0; t < CL; t++) {
        const float dx = dtv[t] * xcv[t];
        float y = 0.f;
        #pragma unroll
        for (int n = 0; n < 16; n++) {
            h[n] = __expf(dtv[t] * Av[n]) * h[n] + dx * Bsh[t][n];
            y += h[n] * Csh[t][n];
        }
        y += xcv[t] * Dv;
        y *= zv[t] / (1.f + __expf(-zv[t]));
        yb[(base + t) * DI + d] = (__bf16)y;
    }
}

// -------- out = x + LayerNorm(sum of 4 bf16 partials) ------------------------
__global__ __launch_bounds__(256) void ln_add(
    const float* __restrict__ x, const __bf16* __restrict__ mpart,
    const float* __restrict__ gamma, const float* __restrict__ beta,
    float* __restrict__ out)
{
    const int tok = blockIdx.x;
    const int tid = threadIdx.x;
    const int lane = tid & 63, wave = tid >> 6;
    __shared__ float red[4];
    __shared__ float stats[2];

    float4 v = {0.f, 0.f, 0.f, 0.f};
    #pragma unroll
    for (int p = 0; p < 4; p++) {
        const bf16x4 mv = *reinterpret_cast<const bf16x4*>(
            &mpart[((size_t)p * NTOK + tok) * DM + tid * 4]);
        v.x += (float)mv[0]; v.y += (float)mv[1];
        v.z += (float)mv[2]; v.w += (float)mv[3];
    }
    float s = v.x + v.y + v.z + v.w;
    #pragma unroll
    for (int o = 32; o > 0; o >>= 1) s += __shfl_down(s, o, 64);
    if (lane == 0) red[wave] = s;
    __syncthreads();
    if (tid == 0) stats[0] = (red[0] + red[1] + red[2] + red[3]) * (1.f / DM);
    __syncthreads();
    const float mu = stats[0];
    const float dx = v.x - mu, dy = v.y - mu, dz = v.z - mu, dw = v.w - mu;
    float q = dx * dx + dy * dy + dz * dz + dw * dw;
    #pragma unroll
    for (int o = 32; o > 0; o >>= 1) q += __shfl_down(q, o, 64);
    if (lane == 0) red[wave] = q;
    __syncthreads();
    if (tid == 0)
        stats[1] = rsqrtf((red[0] + red[1] + red[2] + red[3]) * (1.f / DM) + 1e-6f);
    __syncthreads();
    const float rs = stats[1];

    const float4 g  = reinterpret_cast<const float4*>(gamma)[tid];
    const float4 bb = reinterpret_cast<const float4*>(beta)[tid];
    const float4 xv = reinterpret_cast<const float4*>(&x[(size_t)tok * DM])[tid];
    float4 o;
    o.x = xv.x + dx * rs * g.x + bb.x;
    o.y = xv.y + dy * rs * g.y + bb.y;
    o.z = xv.z + dz * rs * g.z + bb.z;
    o.w = xv.w + dw * rs * g.w + bb.w;
    reinterpret_cast<float4*>(&out[(size_t)tok * DM])[tid] = o;
}

extern "C" void kernel_launch(void* const* d_in, const int* in_sizes, int n_in,
                              void* d_out, int out_size, void* d_ws, size_t ws_size,
                              hipStream_t stream)
{
    const float* x      = (const float*)d_in[0];
    const float* W_in   = (const float*)d_in[1];
    const float* conv_w = (const float*)d_in[2];
    const float* conv_b = (const float*)d_in[3];
    const float* W_xprj = (const float*)d_in[4];
    const float* W_dt   = (const float*)d_in[5];
    const float* b_dt   = (const float*)d_in[6];
    const float* A_log  = (const float*)d_in[7];
    const float* D_par  = (const float*)d_in[8];
    const float* W_out  = (const float*)d_in[9];
    const float* gamma  = (const float*)d_in[10];
    const float* beta   = (const float*)d_in[11];
    float* out = (float*)d_out;

    // workspace layout (byte offsets, non-aliasing, ~113 MB)
    char* w = (char*)d_ws;
    __bf16* xzb    = (__bf16*)(w + 0);          // 16 MB [NTOK][4096] (xi|z)
    __bf16* xcb    = (__bf16*)(w + 16777216);   //  8 MB [NTOK][DI]
    float*  xdbl   = (float*) (w + 25165824);   //  1 MB [NTOK][128]
    __bf16* dtb    = (__bf16*)(w + 26214400);   //  8 MB [NTOK][DI]
    __bf16* mpart  = (__bf16*)(w + 34603008);   // 16 MB [4][NTOK][DM]
    __bf16* hpart  = (__bf16*)(w + 51380224);   // 16 MB [NB*CK][DI][16]
    __bf16* hentry = (__bf16*)(w + 68157440);   // 16 MB [NB*CK][DI][16]
    float*  sdtb   = (float*) (w + 84934656);   //  2 MB [NB*CK][DI]
    __bf16* xb     = (__bf16*)(w + 87031808);   //  4 MB [NTOK][DM]
    __bf16* W_inT  = (__bf16*)(w + 91226112);   //  8 MB [4096][DM]
    __bf16* W_outT = (__bf16*)(w + 99614720);   //  4 MB [DM][DI]
    __bf16* W_xprT = (__bf16*)(w + 103809024);  // .5 MB [128][DI]
    __bf16* WdtT   = (__bf16*)(w + 104333312);  // .25MB [DI][64]
    __bf16* yb     = (__bf16*)(w + 104595456);  //  8 MB [NTOK][DI]

    // 0. fused prep
    prep<<<PREP_BLOCKS, 256, 0, stream>>>(
        x, W_in, W_out, W_dt, W_xprj, xb, W_inT, W_outT, WdtT, W_xprT, xdbl);

    // 1. xz = x @ W_in  (M=2048, N=4096, K=1024) -> bf16, TN=128 piped
    gemm_bf16<3, 2, 128><<<dim3(32, 16, 1), 256, 0, stream>>>(
        xb, W_inT, xzb, NTOK, 2 * DI, DM, 2 * DI, nullptr);

    // 2. conv + silu -> bf16
    conv_silu<<<(NTOK * DI / 8) / 256, 256, 0, stream>>>(xzb, conv_w, conv_b, xcb);

    // 3. x_dbl = xc @ W_xproj  (N=128 pad, K=2048), split-K=16, atomic f32
    gemm_bf16<1, 0, 128><<<dim3(1, 16, 16), 256, 0, stream>>>(
        xcb, W_xprT, xdbl, NTOK, XNP, DI, XNP, nullptr);

    // 4. dt = softplus(dt_r @ W_dt + b_dt) -> bf16, TN=64
    gemm_bf16<2, 0, 64><<<dim3(32, 16, 1), 256, 0, stream>>>(
        (const __bf16*)xdbl, WdtT, dtb, NTOK, DI, DTR, DI, b_dt);

    // 5. chunked selective scan (CK=128 chunks of CL=8 -> 2048 blocks A/C)
    scan_partial<<<dim3(DI / 256, CK, NB), 256, 0, stream>>>(
        xcb, xdbl, dtb, A_log, hpart, sdtb);
    scan_combine<<<NB * DI * DS / 256, 256, 0, stream>>>(A_log, sdtb, hpart, hentry);
    scan_final<<<dim3(DI / 256, CK, NB), 256, 0, stream>>>(
        xzb, xcb, xdbl, dtb, A_log, D_par, hentry, yb);

    // 6. m partials = y @ W_out  (split-K=4, TN=128 piped, bf16 partials)
    gemm_bf16<3, 1, 128><<<dim3(8, 16, 4), 256, 0, stream>>>(
        yb, W_outT, mpart, NTOK, DM, DI, DM, nullptr);

    // 7. out = x + LN(sum of partials)
    ln_add<<<NTOK, 256, 0, stream>>>(x, mpart, gamma, beta, out);
}

// Round 17
// 149.819 us; speedup vs baseline: 1.0866x; 1.0363x over previous
//
#include <hip/hip_runtime.h>
#include <math.h>

#define DM   1024
#define DI   2048
#define DS   16
#define DTR  64
#define NB   2
#define SEQL 1024
#define NTOK (NB*SEQL)
#define XND  96   /* DTR + 2*DS */
#define XNP  128  /* padded xproj width */
#define CK   128  /* scan chunks */
#define CL   8    /* chunk length */
#define NPART 2   /* out-proj split-K partials */

typedef __bf16 bf16x8 __attribute__((ext_vector_type(8)));
typedef __bf16 bf16x4 __attribute__((ext_vector_type(4)));
typedef float  f32x4  __attribute__((ext_vector_type(4)));

// ------------- fused prep: zeroing + conversions + transposes ----------------
#define PREP_BLOCKS 3872

__device__ inline void trans_tile64(const float* __restrict__ W,
                                    __bf16* __restrict__ WT, int K, int N,
                                    int n0, int k0, int tid, __bf16 (*t)[65])
{
    const int tx = tid & 63, ty = tid >> 6;   // ty 0..3
    #pragma unroll
    for (int i = 0; i < 16; i++)
        t[ty * 16 + i][tx] = (__bf16)W[(size_t)(k0 + ty * 16 + i) * N + n0 + tx];
    __syncthreads();
    #pragma unroll
    for (int i = 0; i < 16; i++)
        WT[(size_t)(n0 + ty * 16 + i) * K + k0 + tx] = t[tx][ty * 16 + i];
}

__global__ __launch_bounds__(256) void prep(
    const float* __restrict__ x, const float* __restrict__ W_in,
    const float* __restrict__ W_out, const float* __restrict__ W_dt,
    const float* __restrict__ W_xprj,
    __bf16* __restrict__ xb, __bf16* __restrict__ W_inT,
    __bf16* __restrict__ W_outT, __bf16* __restrict__ WdtT,
    __bf16* __restrict__ W_xprT, float* __restrict__ xdbl)
{
    __shared__ __bf16 t[64][65];
    int bid = blockIdx.x;
    const int tid = threadIdx.x;

    if (bid < 256) {                        // R0: zero xdbl
        const int i = bid * 1024 + tid * 4;
        const float4 z = {0.f, 0.f, 0.f, 0.f};
        *reinterpret_cast<float4*>(&xdbl[i]) = z;
        return;
    }
    bid -= 256;
    if (bid < 1024) {                       // R1: cvt x -> xb
        const int e = (bid * 256 + tid) * 8;
        const float4 v0 = *reinterpret_cast<const float4*>(&x[e]);
        const float4 v1 = *reinterpret_cast<const float4*>(&x[e + 4]);
        bf16x8 o;
        o[0] = (__bf16)v0.x; o[1] = (__bf16)v0.y; o[2] = (__bf16)v0.z; o[3] = (__bf16)v0.w;
        o[4] = (__bf16)v1.x; o[5] = (__bf16)v1.y; o[6] = (__bf16)v1.z; o[7] = (__bf16)v1.w;
        *reinterpret_cast<bf16x8*>(&xb[e]) = o;
        return;
    }
    bid -= 1024;
    if (bid < 1024) {                       // R2: W_in [1024][4096] -> T
        trans_tile64(W_in, W_inT, DM, 2 * DI, (bid & 63) * 64, (bid >> 6) * 64, tid, t);
        return;
    }
    bid -= 1024;
    if (bid < 512) {                        // R3: W_out [2048][1024] -> T
        trans_tile64(W_out, W_outT, DI, DM, (bid & 15) * 64, (bid >> 4) * 64, tid, t);
        return;
    }
    bid -= 512;
    if (bid < 32) {                         // R4: W_dt [64][2048] -> T
        trans_tile64(W_dt, WdtT, DTR, DI, bid * 64, 0, tid, t);
        return;
    }
    bid -= 32;
    {                                       // R5: xproj transpose+pad
        const int idx = bid * 256 + tid;
        const int k = idx & (DI - 1);
        const int n = idx >> 11;
        W_xprT[(size_t)n * DI + k] = (n < XND) ? (__bf16)W_xprj[(size_t)k * XND + n]
                                               : (__bf16)0.f;
    }
}

// -------- bf16 MFMA GEMM, 128xTN tile, BK=64, XOR-swizzled LDS ---------------
// PIPE path (MODE 1/3): double-buffered with COUNTED vmcnt + raw s_barrier
// (m201/T4 discipline). MODE 2: classic 2-barrier loop (nt==1 for dt).
// MODE 1: atomicAdd f32 | 2: softplus(acc+bias)->bf16 LDS-bounce |
// 3: bf16 LDS-bounce (per-z partial offset when gridDim.z>1).
// SWZ 0: none | 1: XCD swizzle row-major | 2: XCD swizzle col-major.
template<int MODE, int SWZ, int TN>
__global__ __launch_bounds__(256) void gemm_bf16(
    const __bf16* __restrict__ A, const __bf16* __restrict__ Bt,
    void* __restrict__ Cp, int M, int N, int K, int ldc,
    const float* __restrict__ bias)
{
    constexpr int NFR = TN / 32;            // n-fragments per wave per ks
    constexpr bool PIPE = (MODE != 2);
    constexpr int ASZ = 128 * 64, BSZ = TN * 64;
    constexpr int STG = (PIPE ? 2 : 1) * (ASZ + BSZ);
    constexpr int SMEM = (STG > 128 * TN) ? STG : 128 * TN;
    __shared__ __bf16 smem[SMEM];
    const int tid  = threadIdx.x;
    const int lane = tid & 63;
    const int wid  = tid >> 6;
    const int wr   = wid >> 1, wc = wid & 1;

    int bx = blockIdx.x, by = blockIdx.y;
    if (SWZ != 0) {
        const int gx = gridDim.x, gy = gridDim.y;
        const int nxy = gx * gy;            // multiple of 8
        const int q = nxy >> 3;
        int lin = by * gx + bx;
        lin = (lin & 7) * q + (lin >> 3);
        if (SWZ == 1) { by = lin / gx; bx = lin % gx; }
        else          { bx = lin / gy; by = lin % gy; }
    }
    const int brow = by * 128, bcol = bx * TN;
    const int kper = K / gridDim.z;
    const int kbeg = blockIdx.z * kper, kend = kbeg + kper;

    f32x4 acc[4][NFR] = {};

    auto stage = [&](int buf, int k0) {
        __bf16* As = smem + buf * (ASZ + BSZ);
        __bf16* Bs = As + ASZ;
        if (MODE == 2) {
            const float* Af = reinterpret_cast<const float*>(A);
            #pragma unroll
            for (int p = 0; p < 4; p++) {
                const int i = p * 256 + tid;
                const int r = i >> 3;
                const int j = i & 7;
                const float4 v0 = *reinterpret_cast<const float4*>(
                    &Af[(size_t)(brow + r) * XNP + j * 8]);
                const float4 v1 = *reinterpret_cast<const float4*>(
                    &Af[(size_t)(brow + r) * XNP + j * 8 + 4]);
                bf16x8 o;
                o[0] = (__bf16)v0.x; o[1] = (__bf16)v0.y; o[2] = (__bf16)v0.z; o[3] = (__bf16)v0.w;
                o[4] = (__bf16)v1.x; o[5] = (__bf16)v1.y; o[6] = (__bf16)v1.z; o[7] = (__bf16)v1.w;
                *reinterpret_cast<bf16x8*>(&As[r * 64 + ((j ^ (r & 7))) * 8]) = o;
            }
        } else {
            #pragma unroll
            for (int p = 0; p < 4; p++) {
                const int i = p * 256 + tid;
                const int r = i >> 3;
                const int gc = ((i & 7) ^ (r & 7)) * 8;
                __builtin_amdgcn_global_load_lds(
                    (const __attribute__((address_space(1))) void*)(A + (size_t)(brow + r) * K + k0 + gc),
                    (__attribute__((address_space(3))) void*)(&As[i * 8]), 16, 0, 0);
            }
        }
        #pragma unroll
        for (int p = 0; p < TN / 32; p++) {
            const int i = p * 256 + tid;
            const int r = i >> 3;
            const int gc = ((i & 7) ^ (r & 7)) * 8;
            __builtin_amdgcn_global_load_lds(
                (const __attribute__((address_space(1))) void*)(Bt + (size_t)(bcol + r) * K + k0 + gc),
                (__attribute__((address_space(3))) void*)(&Bs[i * 8]), 16, 0, 0);
        }
    };

    auto compute = [&](int buf) {
        const __bf16* As = smem + buf * (ASZ + BSZ);
        const __bf16* Bs = As + ASZ;
        bf16x8 a[2][4], b[2][NFR];
        const int rA = wr * 64 + (lane & 15);
        const int rB = wc * (TN / 2) + (lane & 15);
        const int cq = lane >> 4;
        const int rx = lane & 7;
        #pragma unroll
        for (int ks = 0; ks < 2; ks++) {
            const int sl = ((ks * 4 + cq) ^ rx) * 8;
            #pragma unroll
            for (int m = 0; m < 4; m++)
                a[ks][m] = *reinterpret_cast<const bf16x8*>(&As[(rA + m * 16) * 64 + sl]);
            #pragma unroll
            for (int n = 0; n < NFR; n++)
                b[ks][n] = *reinterpret_cast<const bf16x8*>(&Bs[(rB + n * 16) * 64 + sl]);
        }
        #pragma unroll
        for (int ks = 0; ks < 2; ks++)
            #pragma unroll
            for (int m = 0; m < 4; m++)
                #pragma unroll
                for (int n = 0; n < NFR; n++)
                    acc[m][n] = __builtin_amdgcn_mfma_f32_16x16x32_bf16(
                        a[ks][m], b[ks][n], acc[m][n], 0, 0, 0);
    };

    const int nt = (kend - kbeg) >> 6;
    if constexpr (PIPE) {
        constexpr int LOADS = 4 + TN / 32;   // per-thread gload_lds per stage
        stage(0, kbeg);
        int cur = 0;
        for (int t = 0; t < nt; t++) {
            if (t + 1 < nt) {
                stage(cur ^ 1, kbeg + ((t + 1) << 6));
                asm volatile("s_waitcnt vmcnt(%0)" :: "n"(LOADS) : "memory");
            } else {
                asm volatile("s_waitcnt vmcnt(0)" ::: "memory");
            }
            __builtin_amdgcn_s_barrier();          // cur's tile ready for all
            __builtin_amdgcn_sched_barrier(0);
            compute(cur);
            __builtin_amdgcn_sched_barrier(0);
            __builtin_amdgcn_s_barrier();          // all done reading cur
            cur ^= 1;
        }
    } else {
        for (int k0 = kbeg; k0 < kend; k0 += 64) {
            __syncthreads();
            stage(0, k0);
            __syncthreads();
            compute(0);
        }
    }

    const int crl = wr * 64 + (lane >> 4) * 4;   // local row base
    const int ccl = wc * (TN / 2) + (lane & 15); // local col base

    if (MODE == 1) {
        #pragma unroll
        for (int m = 0; m < 4; m++)
            #pragma unroll
            for (int n = 0; n < NFR; n++) {
                const int col = bcol + ccl + n * 16;
                #pragma unroll
                for (int j = 0; j < 4; j++)
                    atomicAdd(&((float*)Cp)[(size_t)(brow + crl + m * 16 + j) * ldc + col],
                              acc[m][n][j]);
            }
    } else {
        // ---- LDS-bounce epilogue: fragment -> LDS -> coalesced bf16x8 ----
        __syncthreads();
        __bf16* Cs = smem;
        #pragma unroll
        for (int m = 0; m < 4; m++)
            #pragma unroll
            for (int n = 0; n < NFR; n++) {
                #pragma unroll
                for (int j = 0; j < 4; j++) {
                    float v = acc[m][n][j];
                    if (MODE == 2) {
                        v += bias[bcol + ccl + n * 16];
                        v = fmaxf(v, 0.f) + log1pf(__expf(-fabsf(v)));
                    }
                    Cs[(crl + m * 16 + j) * TN + ccl + n * 16] = (__bf16)v;
                }
            }
        __syncthreads();
        __bf16* Cb = (__bf16*)Cp +
            (size_t)blockIdx.z * ((MODE == 3) ? (size_t)M * ldc : 0);
        constexpr int CHUNKS = 128 * TN / 8;
        #pragma unroll
        for (int p = 0; p < CHUNKS / 256; p++) {
            const int i = p * 256 + tid;
            const int r = i / (TN / 8);
            const int cc = (i % (TN / 8)) * 8;
            *reinterpret_cast<bf16x8*>(&Cb[(size_t)(brow + r) * ldc + bcol + cc]) =
                *reinterpret_cast<const bf16x8*>(&Cs[r * TN + cc]);
        }
    }
}

// -------- depthwise causal conv (k=4) + bias + SiLU, 8 ch/thread -------------
__global__ __launch_bounds__(256) void conv_silu(
    const __bf16* __restrict__ xzb, const float* __restrict__ conv_w,
    const float* __restrict__ conv_b, __bf16* __restrict__ xcb)
{
    const int g  = blockIdx.x * 256 + threadIdx.x;
    const int d0 = (g & 255) * 8;
    const int tok = g >> 8;
    const int t   = tok & (SEQL - 1);

    float4 wv[8];
    #pragma unroll
    for (int j = 0; j < 8; j++)
        wv[j] = *reinterpret_cast<const float4*>(&conv_w[(d0 + j) * 4]);
    float acc[8];
    {
        const float4 b0 = *reinterpret_cast<const float4*>(&conv_b[d0]);
        const float4 b1 = *reinterpret_cast<const float4*>(&conv_b[d0 + 4]);
        acc[0] = b0.x; acc[1] = b0.y; acc[2] = b0.z; acc[3] = b0.w;
        acc[4] = b1.x; acc[5] = b1.y; acc[6] = b1.z; acc[7] = b1.w;
    }
    #pragma unroll
    for (int k = 0; k < 4; k++) {
        const int tt = t + k - 3;
        if (tt >= 0) {
            const bf16x8 v = *reinterpret_cast<const bf16x8*>(
                &xzb[(size_t)(tok + k - 3) * (2 * DI) + d0]);
            #pragma unroll
            for (int j = 0; j < 8; j++) {
                const float wk = (k == 0) ? wv[j].x : (k == 1) ? wv[j].y
                               : (k == 2) ? wv[j].z : wv[j].w;
                acc[j] += (float)v[j] * wk;
            }
        }
    }
    bf16x8 o;
    #pragma unroll
    for (int j = 0; j < 8; j++) {
        const float a = acc[j];
        o[j] = (__bf16)(a / (1.f + __expf(-a)));
    }
    *reinterpret_cast<bf16x8*>(&xcb[(size_t)g * 8]) = o;
}

// -------- scan pass A: per-chunk local scan from h=0, bf16 h out -------------
__global__ __launch_bounds__(256) void scan_partial(
    const __bf16* __restrict__ xcb, const float* __restrict__ xdbl,
    const __bf16* __restrict__ dtb, const float* __restrict__ A_log,
    __bf16* __restrict__ hpart, float* __restrict__ sdtb)
{
    __shared__ float Bsh[CL][16];
    const int tid = threadIdx.x;
    const int d = blockIdx.x * 256 + tid;
    const int c = blockIdx.y, b = blockIdx.z;
    const size_t base = (size_t)b * SEQL + c * CL;
    {
        const int st = tid >> 4, sg = tid & 15;
        if (st < CL) Bsh[st][sg] = xdbl[(base + st) * XNP + DTR + sg];
    }
    float dtv[CL], xcv[CL];
    #pragma unroll
    for (int t = 0; t < CL; t++) {
        dtv[t] = (float)dtb[(base + t) * DI + d];
        xcv[t] = (float)xcb[(base + t) * DI + d];
    }
    float Av[16];
    #pragma unroll
    for (int i = 0; i < 4; i++) {
        const float4 v = *reinterpret_cast<const float4*>(&A_log[(size_t)d * 16 + i * 4]);
        Av[i*4+0] = -__expf(v.x); Av[i*4+1] = -__expf(v.y);
        Av[i*4+2] = -__expf(v.z); Av[i*4+3] = -__expf(v.w);
    }
    __syncthreads();
    float h[16] = {};
    float sdt = 0.f;
    #pragma unroll
    for (int t = 0; t < CL; t++) {
        sdt += dtv[t];
        const float dx = dtv[t] * xcv[t];
        #pragma unroll
        for (int n = 0; n < 16; n++)
            h[n] = __expf(dtv[t] * Av[n]) * h[n] + dx * Bsh[t][n];
    }
    const size_t ob = ((size_t)(b * CK + c) * DI + d) * 16;
    bf16x8 o0, o1;
    #pragma unroll
    for (int i = 0; i < 8; i++) { o0[i] = (__bf16)h[i]; o1[i] = (__bf16)h[i + 8]; }
    *reinterpret_cast<bf16x8*>(&hpart[ob])     = o0;
    *reinterpret_cast<bf16x8*>(&hpart[ob + 8]) = o1;
    sdtb[(size_t)(b * CK + c) * DI + d] = sdt;
}

// -------- scan pass B: chunk combine, hpart -> hentry (bf16), batched --------
__global__ __launch_bounds__(256) void scan_combine(
    const float* __restrict__ A_log, const float* __restrict__ sdtb,
    const __bf16* __restrict__ hpart, __bf16* __restrict__ hentry)
{
    const int idx = blockIdx.x * 256 + threadIdx.x;
    const int n = idx & 15;
    const int d = (idx >> 4) & (DI - 1);
    const int b = idx >> 15;
    const float A = -__expf(A_log[(size_t)d * 16 + n]);
    float h = 0.f;
    for (int cb = 0; cb < CK / 16; cb++) {
        float hl[16], sv[16];
        #pragma unroll
        for (int j = 0; j < 16; j++) {
            const int c = cb * 16 + j;
            hl[j] = (float)hpart[((size_t)(b * CK + c) * DI + d) * 16 + n];
            sv[j] = sdtb[(size_t)(b * CK + c) * DI + d];
        }
        #pragma unroll
        for (int j = 0; j < 16; j++) {
            const int c = cb * 16 + j;
            hentry[((size_t)(b * CK + c) * DI + d) * 16 + n] = (__bf16)h;
            h = __expf(A * sv[j]) * h + hl[j];
        }
    }
}

// -------- scan pass C: seeded re-scan, emit y (D-skip + z-gate) as bf16 ------
__global__ __launch_bounds__(256) void scan_final(
    const __bf16* __restrict__ xzb, const __bf16* __restrict__ xcb,
    const float* __restrict__ xdbl, const __bf16* __restrict__ dtb,
    const float* __restrict__ A_log, const float* __restrict__ Dp,
    const __bf16* __restrict__ hentry, __bf16* __restrict__ yb)
{
    __shared__ float Bsh[CL][16];
    __shared__ float Csh[CL][16];
    const int tid = threadIdx.x;
    const int d = blockIdx.x * 256 + tid;
    const int c = blockIdx.y, b = blockIdx.z;
    const size_t base = (size_t)b * SEQL + c * CL;
    {
        const int st = tid >> 4, sg = tid & 15;
        if (st < CL)
            Bsh[st][sg] = xdbl[(base + st) * XNP + DTR + sg];
        else if (st < 2 * CL)
            Csh[st - CL][sg] = xdbl[(base + st - CL) * XNP + DTR + DS + sg];
    }
    float dtv[CL], xcv[CL], zv[CL];
    #pragma unroll
    for (int t = 0; t < CL; t++) {
        dtv[t] = (float)dtb[(base + t) * DI + d];
        xcv[t] = (float)xcb[(base + t) * DI + d];
        zv[t]  = (float)xzb[(base + t) * (2 * DI) + DI + d];
    }
    float Av[16];
    #pragma unroll
    for (int i = 0; i < 4; i++) {
        const float4 v = *reinterpret_cast<const float4*>(&A_log[(size_t)d * 16 + i * 4]);
        Av[i*4+0] = -__expf(v.x); Av[i*4+1] = -__expf(v.y);
        Av[i*4+2] = -__expf(v.z); Av[i*4+3] = -__expf(v.w);
    }
    float h[16];
    const size_t ob = ((size_t)(b * CK + c) * DI + d) * 16;
    {
        const bf16x8 v0 = *reinterpret_cast<const bf16x8*>(&hentry[ob]);
        const bf16x8 v1 = *reinterpret_cast<const bf16x8*>(&hentry[ob + 8]);
        #pragma unroll
        for (int i = 0; i < 8; i++) { h[i] = (float)v0[i]; h[i + 8] = (float)v1[i]; }
    }
    const float Dv = Dp[d];
    __syncthreads();
    #pragma unroll
    for (int t = 0; t < CL; t++) {
        const float dx = dtv[t] * xcv[t];
        float y = 0.f;
        #pragma unroll
        for (int n = 0; n < 16; n++) {
            h[n] = __expf(dtv[t] * Av[n]) * h[n] + dx * Bsh[t][n];
            y += h[n] * Csh[t][n];
        }
        y += xcv[t] * Dv;
        y *= zv[t] / (1.f + __expf(-zv[t]));
        yb[(base + t) * DI + d] = (__bf16)y;
    }
}

// -------- out = x + LayerNorm(sum of NPART bf16 partials), 1-pass stats ------
__global__ __launch_bounds__(256) void ln_add(
    const float* __restrict__ x, const __bf16* __restrict__ mpart,
    const float* __restrict__ gamma, const float* __restrict__ beta,
    float* __restrict__ out)
{
    const int tok = blockIdx.x;
    const int tid = threadIdx.x;
    const int lane = tid & 63, wave = tid >> 6;
    __shared__ float red1[4], red2[4];
    __shared__ float stats[2];

    float4 v = {0.f, 0.f, 0.f, 0.f};
    #pragma unroll
    for (int p = 0; p < NPART; p++) {
        const bf16x4 mv = *reinterpret_cast<const bf16x4*>(
            &mpart[((size_t)p * NTOK + tok) * DM + tid * 4]);
        v.x += (float)mv[0]; v.y += (float)mv[1];
        v.z += (float)mv[2]; v.w += (float)mv[3];
    }
    float s1 = v.x + v.y + v.z + v.w;
    float s2 = v.x * v.x + v.y * v.y + v.z * v.z + v.w * v.w;
    #pragma unroll
    for (int o = 32; o > 0; o >>= 1) {
        s1 += __shfl_down(s1, o, 64);
        s2 += __shfl_down(s2, o, 64);
    }
    if (lane == 0) { red1[wave] = s1; red2[wave] = s2; }
    __syncthreads();
    if (tid == 0) {
        const float m1 = (red1[0] + red1[1] + red1[2] + red1[3]) * (1.f / DM);
        const float m2 = (red2[0] + red2[1] + red2[2] + red2[3]) * (1.f / DM);
        stats[0] = m1;
        stats[1] = rsqrtf(fmaxf(m2 - m1 * m1, 0.f) + 1e-6f);
    }
    __syncthreads();
    const float mu = stats[0];
    const float rs = stats[1];

    const float4 g  = reinterpret_cast<const float4*>(gamma)[tid];
    const float4 bb = reinterpret_cast<const float4*>(beta)[tid];
    const float4 xv = reinterpret_cast<const float4*>(&x[(size_t)tok * DM])[tid];
    float4 o;
    o.x = xv.x + (v.x - mu) * rs * g.x + bb.x;
    o.y = xv.y + (v.y - mu) * rs * g.y + bb.y;
    o.z = xv.z + (v.z - mu) * rs * g.z + bb.z;
    o.w = xv.w + (v.w - mu) * rs * g.w + bb.w;
    reinterpret_cast<float4*>(&out[(size_t)tok * DM])[tid] = o;
}

extern "C" void kernel_launch(void* const* d_in, const int* in_sizes, int n_in,
                              void* d_out, int out_size, void* d_ws, size_t ws_size,
                              hipStream_t stream)
{
    const float* x      = (const float*)d_in[0];
    const float* W_in   = (const float*)d_in[1];
    const float* conv_w = (const float*)d_in[2];
    const float* conv_b = (const float*)d_in[3];
    const float* W_xprj = (const float*)d_in[4];
    const float* W_dt   = (const float*)d_in[5];
    const float* b_dt   = (const float*)d_in[6];
    const float* A_log  = (const float*)d_in[7];
    const float* D_par  = (const float*)d_in[8];
    const float* W_out  = (const float*)d_in[9];
    const float* gamma  = (const float*)d_in[10];
    const float* beta   = (const float*)d_in[11];
    float* out = (float*)d_out;

    // workspace layout (byte offsets, non-aliasing, ~113 MB)
    char* w = (char*)d_ws;
    __bf16* xzb    = (__bf16*)(w + 0);          // 16 MB [NTOK][4096] (xi|z)
    __bf16* xcb    = (__bf16*)(w + 16777216);   //  8 MB [NTOK][DI]
    float*  xdbl   = (float*) (w + 25165824);   //  1 MB [NTOK][128]
    __bf16* dtb    = (__bf16*)(w + 26214400);   //  8 MB [NTOK][DI]
    __bf16* mpart  = (__bf16*)(w + 34603008);   //  8 MB [NPART][NTOK][DM]
    __bf16* hpart  = (__bf16*)(w + 51380224);   // 16 MB [NB*CK][DI][16]
    __bf16* hentry = (__bf16*)(w + 68157440);   // 16 MB [NB*CK][DI][16]
    float*  sdtb   = (float*) (w + 84934656);   //  2 MB [NB*CK][DI]
    __bf16* xb     = (__bf16*)(w + 87031808);   //  4 MB [NTOK][DM]
    __bf16* W_inT  = (__bf16*)(w + 91226112);   //  8 MB [4096][DM]
    __bf16* W_outT = (__bf16*)(w + 99614720);   //  4 MB [DM][DI]
    __bf16* W_xprT = (__bf16*)(w + 103809024);  // .5 MB [128][DI]
    __bf16* WdtT   = (__bf16*)(w + 104333312);  // .25MB [DI][64]
    __bf16* yb     = (__bf16*)(w + 104595456);  //  8 MB [NTOK][DI]

    // 0. fused prep
    prep<<<PREP_BLOCKS, 256, 0, stream>>>(
        x, W_in, W_out, W_dt, W_xprj, xb, W_inT, W_outT, WdtT, W_xprT, xdbl);

    // 1. xz = x @ W_in  (M=2048, N=4096, K=1024) -> bf16, TN=128 piped
    gemm_bf16<3, 2, 128><<<dim3(32, 16, 1), 256, 0, stream>>>(
        xb, W_inT, xzb, NTOK, 2 * DI, DM, 2 * DI, nullptr);

    // 2. conv + silu -> bf16
    conv_silu<<<(NTOK * DI / 8) / 256, 256, 0, stream>>>(xzb, conv_w, conv_b, xcb);

    // 3. x_dbl = xc @ W_xproj  (N=128 pad, K=2048), split-K=16, atomic f32
    gemm_bf16<1, 0, 128><<<dim3(1, 16, 16), 256, 0, stream>>>(
        xcb, W_xprT, xdbl, NTOK, XNP, DI, XNP, nullptr);

    // 4. dt = softplus(dt_r @ W_dt + b_dt) -> bf16, TN=64
    gemm_bf16<2, 0, 64><<<dim3(32, 16, 1), 256, 0, stream>>>(
        (const __bf16*)xdbl, WdtT, dtb, NTOK, DI, DTR, DI, b_dt);

    // 5. chunked selective scan (CK=128 chunks of CL=8 -> 2048 blocks A/C)
    scan_partial<<<dim3(DI / 256, CK, NB), 256, 0, stream>>>(
        xcb, xdbl, dtb, A_log, hpart, sdtb);
    scan_combine<<<NB * DI * DS / 256, 256, 0, stream>>>(A_log, sdtb, hpart, hentry);
    scan_final<<<dim3(DI / 256, CK, NB), 256, 0, stream>>>(
        xzb, xcb, xdbl, dtb, A_log, D_par, hentry, yb);

    // 6. m partials = y @ W_out  (split-K=2, TN=128 piped, bf16 partials)
    gemm_bf16<3, 1, 128><<<dim3(8, 16, NPART), 256, 0, stream>>>(
        yb, W_outT, mpart, NTOK, DM, DI, DM, nullptr);

    // 7. out = x + LN(sum of partials), single-pass stats
    ln_add<<<NTOK, 256, 0, stream>>>(x, mpart, gamma, beta, out);
}

// Round 18
// 149.773 us; speedup vs baseline: 1.0869x; 1.0003x over previous
//
#include <hip/hip_runtime.h>
#include <math.h>

#define DM   1024
#define DI   2048
#define DS   16
#define DTR  64
#define NB   2
#define SEQL 1024
#define NTOK (NB*SEQL)
#define XND  96   /* DTR + 2*DS */
#define XNP  128  /* padded xproj width */
#define CK   128  /* scan chunks */
#define CL   8    /* chunk length */
#define NPART 2   /* out-proj split-K partials */

typedef __bf16 bf16x8 __attribute__((ext_vector_type(8)));
typedef __bf16 bf16x4 __attribute__((ext_vector_type(4)));
typedef float  f32x4  __attribute__((ext_vector_type(4)));

// ------------- fused prep: zeroing + conversions + transposes ----------------
#define PREP_BLOCKS 3872

__device__ inline void trans_tile64(const float* __restrict__ W,
                                    __bf16* __restrict__ WT, int K, int N,
                                    int n0, int k0, int tid, __bf16 (*t)[65])
{
    const int tx = tid & 63, ty = tid >> 6;   // ty 0..3
    #pragma unroll
    for (int i = 0; i < 16; i++)
        t[ty * 16 + i][tx] = (__bf16)W[(size_t)(k0 + ty * 16 + i) * N + n0 + tx];
    __syncthreads();
    #pragma unroll
    for (int i = 0; i < 16; i++)
        WT[(size_t)(n0 + ty * 16 + i) * K + k0 + tx] = t[tx][ty * 16 + i];
}

__global__ __launch_bounds__(256) void prep(
    const float* __restrict__ x, const float* __restrict__ W_in,
    const float* __restrict__ W_out, const float* __restrict__ W_dt,
    const float* __restrict__ W_xprj,
    __bf16* __restrict__ xb, __bf16* __restrict__ W_inT,
    __bf16* __restrict__ W_outT, __bf16* __restrict__ WdtT,
    __bf16* __restrict__ W_xprT, float* __restrict__ xdbl)
{
    __shared__ __bf16 t[64][65];
    int bid = blockIdx.x;
    const int tid = threadIdx.x;

    if (bid < 256) {                        // R0: zero xdbl
        const int i = bid * 1024 + tid * 4;
        const float4 z = {0.f, 0.f, 0.f, 0.f};
        *reinterpret_cast<float4*>(&xdbl[i]) = z;
        return;
    }
    bid -= 256;
    if (bid < 1024) {                       // R1: cvt x -> xb
        const int e = (bid * 256 + tid) * 8;
        const float4 v0 = *reinterpret_cast<const float4*>(&x[e]);
        const float4 v1 = *reinterpret_cast<const float4*>(&x[e + 4]);
        bf16x8 o;
        o[0] = (__bf16)v0.x; o[1] = (__bf16)v0.y; o[2] = (__bf16)v0.z; o[3] = (__bf16)v0.w;
        o[4] = (__bf16)v1.x; o[5] = (__bf16)v1.y; o[6] = (__bf16)v1.z; o[7] = (__bf16)v1.w;
        *reinterpret_cast<bf16x8*>(&xb[e]) = o;
        return;
    }
    bid -= 1024;
    if (bid < 1024) {                       // R2: W_in [1024][4096] -> T
        trans_tile64(W_in, W_inT, DM, 2 * DI, (bid & 63) * 64, (bid >> 6) * 64, tid, t);
        return;
    }
    bid -= 1024;
    if (bid < 512) {                        // R3: W_out [2048][1024] -> T
        trans_tile64(W_out, W_outT, DI, DM, (bid & 15) * 64, (bid >> 4) * 64, tid, t);
        return;
    }
    bid -= 512;
    if (bid < 32) {                         // R4: W_dt [64][2048] -> T
        trans_tile64(W_dt, WdtT, DTR, DI, bid * 64, 0, tid, t);
        return;
    }
    bid -= 32;
    {                                       // R5: xproj transpose+pad
        const int idx = bid * 256 + tid;
        const int k = idx & (DI - 1);
        const int n = idx >> 11;
        W_xprT[(size_t)n * DI + k] = (n < XND) ? (__bf16)W_xprj[(size_t)k * XND + n]
                                               : (__bf16)0.f;
    }
}

// -------- bf16 MFMA GEMM, 128xTN tile, BK=64, XOR-swizzled LDS ---------------
// PIPE path (MODE 1/3): double-buffered with COUNTED vmcnt + raw s_barrier.
// MODE 1: atomicAdd f32 | 2: softplus(acc+bias)->bf16 LDS-bounce |
// 3: bf16 LDS-bounce (per-z partial offset when gridDim.z>1).
// SWZ 0: none | 1: XCD row-major chunks | 2: XCD col-major chunks |
// 3: XCD 8x8 2D region (for 32x16 grids; minimizes A+B panel re-fetch).
template<int MODE, int SWZ, int TN>
__global__ __launch_bounds__(256) void gemm_bf16(
    const __bf16* __restrict__ A, const __bf16* __restrict__ Bt,
    void* __restrict__ Cp, int M, int N, int K, int ldc,
    const float* __restrict__ bias)
{
    constexpr int NFR = TN / 32;            // n-fragments per wave per ks
    constexpr bool PIPE = (MODE != 2);
    constexpr int ASZ = 128 * 64, BSZ = TN * 64;
    constexpr int STG = (PIPE ? 2 : 1) * (ASZ + BSZ);
    constexpr int SMEM = (STG > 128 * TN) ? STG : 128 * TN;
    __shared__ __bf16 smem[SMEM];
    const int tid  = threadIdx.x;
    const int lane = tid & 63;
    const int wid  = tid >> 6;
    const int wr   = wid >> 1, wc = wid & 1;

    int bx = blockIdx.x, by = blockIdx.y;
    if (SWZ == 1 || SWZ == 2) {
        const int gx = gridDim.x, gy = gridDim.y;
        const int nxy = gx * gy;            // multiple of 8
        const int q = nxy >> 3;
        int lin = by * gx + bx;
        lin = (lin & 7) * q + (lin >> 3);
        if (SWZ == 1) { by = lin / gx; bx = lin % gx; }
        else          { bx = lin / gy; by = lin % gy; }
    } else if (SWZ == 3) {
        // 8x8 region per XCD; assumes gx==32, gy==16 (regions 4x2)
        const int lin = by * gridDim.x + bx;
        const int r   = lin & 7;            // XCD
        const int idx = lin >> 3;           // 0..63
        bx = (r & 3) * 8 + (idx & 7);
        by = (r >> 2) * 8 + (idx >> 3);
    }
    const int brow = by * 128, bcol = bx * TN;
    const int kper = K / gridDim.z;
    const int kbeg = blockIdx.z * kper, kend = kbeg + kper;

    f32x4 acc[4][NFR] = {};

    auto stage = [&](int buf, int k0) {
        __bf16* As = smem + buf * (ASZ + BSZ);
        __bf16* Bs = As + ASZ;
        if (MODE == 2) {
            const float* Af = reinterpret_cast<const float*>(A);
            #pragma unroll
            for (int p = 0; p < 4; p++) {
                const int i = p * 256 + tid;
                const int r = i >> 3;
                const int j = i & 7;
                const float4 v0 = *reinterpret_cast<const float4*>(
                    &Af[(size_t)(brow + r) * XNP + j * 8]);
                const float4 v1 = *reinterpret_cast<const float4*>(
                    &Af[(size_t)(brow + r) * XNP + j * 8 + 4]);
                bf16x8 o;
                o[0] = (__bf16)v0.x; o[1] = (__bf16)v0.y; o[2] = (__bf16)v0.z; o[3] = (__bf16)v0.w;
                o[4] = (__bf16)v1.x; o[5] = (__bf16)v1.y; o[6] = (__bf16)v1.z; o[7] = (__bf16)v1.w;
                *reinterpret_cast<bf16x8*>(&As[r * 64 + ((j ^ (r & 7))) * 8]) = o;
            }
        } else {
            #pragma unroll
            for (int p = 0; p < 4; p++) {
                const int i = p * 256 + tid;
                const int r = i >> 3;
                const int gc = ((i & 7) ^ (r & 7)) * 8;
                __builtin_amdgcn_global_load_lds(
                    (const __attribute__((address_space(1))) void*)(A + (size_t)(brow + r) * K + k0 + gc),
                    (__attribute__((address_space(3))) void*)(&As[i * 8]), 16, 0, 0);
            }
        }
        #pragma unroll
        for (int p = 0; p < TN / 32; p++) {
            const int i = p * 256 + tid;
            const int r = i >> 3;
            const int gc = ((i & 7) ^ (r & 7)) * 8;
            __builtin_amdgcn_global_load_lds(
                (const __attribute__((address_space(1))) void*)(Bt + (size_t)(bcol + r) * K + k0 + gc),
                (__attribute__((address_space(3))) void*)(&Bs[i * 8]), 16, 0, 0);
        }
    };

    auto compute = [&](int buf) {
        const __bf16* As = smem + buf * (ASZ + BSZ);
        const __bf16* Bs = As + ASZ;
        bf16x8 a[2][4], b[2][NFR];
        const int rA = wr * 64 + (lane & 15);
        const int rB = wc * (TN / 2) + (lane & 15);
        const int cq = lane >> 4;
        const int rx = lane & 7;
        #pragma unroll
        for (int ks = 0; ks < 2; ks++) {
            const int sl = ((ks * 4 + cq) ^ rx) * 8;
            #pragma unroll
            for (int m = 0; m < 4; m++)
                a[ks][m] = *reinterpret_cast<const bf16x8*>(&As[(rA + m * 16) * 64 + sl]);
            #pragma unroll
            for (int n = 0; n < NFR; n++)
                b[ks][n] = *reinterpret_cast<const bf16x8*>(&Bs[(rB + n * 16) * 64 + sl]);
        }
        #pragma unroll
        for (int ks = 0; ks < 2; ks++)
            #pragma unroll
            for (int m = 0; m < 4; m++)
                #pragma unroll
                for (int n = 0; n < NFR; n++)
                    acc[m][n] = __builtin_amdgcn_mfma_f32_16x16x32_bf16(
                        a[ks][m], b[ks][n], acc[m][n], 0, 0, 0);
    };

    const int nt = (kend - kbeg) >> 6;
    if constexpr (PIPE) {
        constexpr int LOADS = 4 + TN / 32;   // per-thread gload_lds per stage
        stage(0, kbeg);
        int cur = 0;
        for (int t = 0; t < nt; t++) {
            if (t + 1 < nt) {
                stage(cur ^ 1, kbeg + ((t + 1) << 6));
                asm volatile("s_waitcnt vmcnt(%0)" :: "n"(LOADS) : "memory");
            } else {
                asm volatile("s_waitcnt vmcnt(0)" ::: "memory");
            }
            __builtin_amdgcn_s_barrier();          // cur's tile ready for all
            __builtin_amdgcn_sched_barrier(0);
            compute(cur);
            __builtin_amdgcn_sched_barrier(0);
            __builtin_amdgcn_s_barrier();          // all done reading cur
            cur ^= 1;
        }
    } else {
        for (int k0 = kbeg; k0 < kend; k0 += 64) {
            __syncthreads();
            stage(0, k0);
            __syncthreads();
            compute(0);
        }
    }

    const int crl = wr * 64 + (lane >> 4) * 4;   // local row base
    const int ccl = wc * (TN / 2) + (lane & 15); // local col base

    if (MODE == 1) {
        #pragma unroll
        for (int m = 0; m < 4; m++)
            #pragma unroll
            for (int n = 0; n < NFR; n++) {
                const int col = bcol + ccl + n * 16;
                #pragma unroll
                for (int j = 0; j < 4; j++)
                    atomicAdd(&((float*)Cp)[(size_t)(brow + crl + m * 16 + j) * ldc + col],
                              acc[m][n][j]);
            }
    } else {
        // ---- LDS-bounce epilogue: fragment -> LDS -> coalesced bf16x8 ----
        __syncthreads();
        __bf16* Cs = smem;
        #pragma unroll
        for (int m = 0; m < 4; m++)
            #pragma unroll
            for (int n = 0; n < NFR; n++) {
                #pragma unroll
                for (int j = 0; j < 4; j++) {
                    float v = acc[m][n][j];
                    if (MODE == 2) {
                        v += bias[bcol + ccl + n * 16];
                        v = fmaxf(v, 0.f) + log1pf(__expf(-fabsf(v)));
                    }
                    Cs[(crl + m * 16 + j) * TN + ccl + n * 16] = (__bf16)v;
                }
            }
        __syncthreads();
        __bf16* Cb = (__bf16*)Cp +
            (size_t)blockIdx.z * ((MODE == 3) ? (size_t)M * ldc : 0);
        constexpr int CHUNKS = 128 * TN / 8;
        #pragma unroll
        for (int p = 0; p < CHUNKS / 256; p++) {
            const int i = p * 256 + tid;
            const int r = i / (TN / 8);
            const int cc = (i % (TN / 8)) * 8;
            *reinterpret_cast<bf16x8*>(&Cb[(size_t)(brow + r) * ldc + bcol + cc]) =
                *reinterpret_cast<const bf16x8*>(&Cs[r * TN + cc]);
        }
    }
}

// -------- depthwise causal conv (k=4) + bias + SiLU, 8 ch/thread -------------
// XCD chunk-swizzled block index: each XCD gets 256 consecutive tokens so
// the 4 overlapping conv taps hit that XCD's L2 instead of re-fetching HBM.
__global__ __launch_bounds__(256) void conv_silu(
    const __bf16* __restrict__ xzb, const float* __restrict__ conv_w,
    const float* __restrict__ conv_b, __bf16* __restrict__ xcb)
{
    const int q  = gridDim.x >> 3;
    const int sb = (blockIdx.x & 7) * q + (blockIdx.x >> 3);
    const int g  = sb * 256 + threadIdx.x;
    const int d0 = (g & 255) * 8;
    const int tok = g >> 8;
    const int t   = tok & (SEQL - 1);

    float4 wv[8];
    #pragma unroll
    for (int j = 0; j < 8; j++)
        wv[j] = *reinterpret_cast<const float4*>(&conv_w[(d0 + j) * 4]);
    float acc[8];
    {
        const float4 b0 = *reinterpret_cast<const float4*>(&conv_b[d0]);
        const float4 b1 = *reinterpret_cast<const float4*>(&conv_b[d0 + 4]);
        acc[0] = b0.x; acc[1] = b0.y; acc[2] = b0.z; acc[3] = b0.w;
        acc[4] = b1.x; acc[5] = b1.y; acc[6] = b1.z; acc[7] = b1.w;
    }
    #pragma unroll
    for (int k = 0; k < 4; k++) {
        const int tt = t + k - 3;
        if (tt >= 0) {
            const bf16x8 v = *reinterpret_cast<const bf16x8*>(
                &xzb[(size_t)(tok + k - 3) * (2 * DI) + d0]);
            #pragma unroll
            for (int j = 0; j < 8; j++) {
                const float wk = (k == 0) ? wv[j].x : (k == 1) ? wv[j].y
                               : (k == 2) ? wv[j].z : wv[j].w;
                acc[j] += (float)v[j] * wk;
            }
        }
    }
    bf16x8 o;
    #pragma unroll
    for (int j = 0; j < 8; j++) {
        const float a = acc[j];
        o[j] = (__bf16)(a / (1.f + __expf(-a)));
    }
    *reinterpret_cast<bf16x8*>(&xcb[(size_t)g * 8]) = o;
}

// -------- scan pass A: per-chunk local scan from h=0, bf16 h out -------------
__global__ __launch_bounds__(256) void scan_partial(
    const __bf16* __restrict__ xcb, const float* __restrict__ xdbl,
    const __bf16* __restrict__ dtb, const float* __restrict__ A_log,
    __bf16* __restrict__ hpart, float* __restrict__ sdtb)
{
    __shared__ float Bsh[CL][16];
    const int tid = threadIdx.x;
    const int d = blockIdx.x * 256 + tid;
    const int c = blockIdx.y, b = blockIdx.z;
    const size_t base = (size_t)b * SEQL + c * CL;
    {
        const int st = tid >> 4, sg = tid & 15;
        if (st < CL) Bsh[st][sg] = xdbl[(base + st) * XNP + DTR + sg];
    }
    float dtv[CL], xcv[CL];
    #pragma unroll
    for (int t = 0; t < CL; t++) {
        dtv[t] = (float)dtb[(base + t) * DI + d];
        xcv[t] = (float)xcb[(base + t) * DI + d];
    }
    float Av[16];
    #pragma unroll
    for (int i = 0; i < 4; i++) {
        const float4 v = *reinterpret_cast<const float4*>(&A_log[(size_t)d * 16 + i * 4]);
        Av[i*4+0] = -__expf(v.x); Av[i*4+1] = -__expf(v.y);
        Av[i*4+2] = -__expf(v.z); Av[i*4+3] = -__expf(v.w);
    }
    __syncthreads();
    float h[16] = {};
    float sdt = 0.f;
    #pragma unroll
    for (int t = 0; t < CL; t++) {
        sdt += dtv[t];
        const float dx = dtv[t] * xcv[t];
        #pragma unroll
        for (int n = 0; n < 16; n++)
            h[n] = __expf(dtv[t] * Av[n]) * h[n] + dx * Bsh[t][n];
    }
    const size_t ob = ((size_t)(b * CK + c) * DI + d) * 16;
    bf16x8 o0, o1;
    #pragma unroll
    for (int i = 0; i < 8; i++) { o0[i] = (__bf16)h[i]; o1[i] = (__bf16)h[i + 8]; }
    *reinterpret_cast<bf16x8*>(&hpart[ob])     = o0;
    *reinterpret_cast<bf16x8*>(&hpart[ob + 8]) = o1;
    sdtb[(size_t)(b * CK + c) * DI + d] = sdt;
}

// -------- scan pass B: chunk combine, hpart -> hentry (bf16), batched --------
__global__ __launch_bounds__(256) void scan_combine(
    const float* __restrict__ A_log, const float* __restrict__ sdtb,
    const __bf16* __restrict__ hpart, __bf16* __restrict__ hentry)
{
    const int idx = blockIdx.x * 256 + threadIdx.x;
    const int n = idx & 15;
    const int d = (idx >> 4) & (DI - 1);
    const int b = idx >> 15;
    const float A = -__expf(A_log[(size_t)d * 16 + n]);
    float h = 0.f;
    for (int cb = 0; cb < CK / 16; cb++) {
        float hl[16], sv[16];
        #pragma unroll
        for (int j = 0; j < 16; j++) {
            const int c = cb * 16 + j;
            hl[j] = (float)hpart[((size_t)(b * CK + c) * DI + d) * 16 + n];
            sv[j] = sdtb[(size_t)(b * CK + c) * DI + d];
        }
        #pragma unroll
        for (int j = 0; j < 16; j++) {
            const int c = cb * 16 + j;
            hentry[((size_t)(b * CK + c) * DI + d) * 16 + n] = (__bf16)h;
            h = __expf(A * sv[j]) * h + hl[j];
        }
    }
}

// -------- scan pass C: seeded re-scan, emit y (D-skip + z-gate) as bf16 ------
__global__ __launch_bounds__(256) void scan_final(
    const __bf16* __restrict__ xzb, const __bf16* __restrict__ xcb,
    const float* __restrict__ xdbl, const __bf16* __restrict__ dtb,
    const float* __restrict__ A_log, const float* __restrict__ Dp,
    const __bf16* __restrict__ hentry, __bf16* __restrict__ yb)
{
    __shared__ float Bsh[CL][16];
    __shared__ float Csh[CL][16];
    const int tid = threadIdx.x;
    const int d = blockIdx.x * 256 + tid;
    const int c = blockIdx.y, b = blockIdx.z;
    const size_t base = (size_t)b * SEQL + c * CL;
    {
        const int st = tid >> 4, sg = tid & 15;
        if (st < CL)
            Bsh[st][sg] = xdbl[(base + st) * XNP + DTR + sg];
        else if (st < 2 * CL)
            Csh[st - CL][sg] = xdbl[(base + st - CL) * XNP + DTR + DS + sg];
    }
    float dtv[CL], xcv[CL], zv[CL];
    #pragma unroll
    for (int t = 0; t < CL; t++) {
        dtv[t] = (float)dtb[(base + t) * DI + d];
        xcv[t] = (float)xcb[(base + t) * DI + d];
        zv[t]  = (float)xzb[(base + t) * (2 * DI) + DI + d];
    }
    float Av[16];
    #pragma unroll
    for (int i = 0; i < 4; i++) {
        const float4 v = *reinterpret_cast<const float4*>(&A_log[(size_t)d * 16 + i * 4]);
        Av[i*4+0] = -__expf(v.x); Av[i*4+1] = -__expf(v.y);
        Av[i*4+2] = -__expf(v.z); Av[i*4+3] = -__expf(v.w);
    }
    float h[16];
    const size_t ob = ((size_t)(b * CK + c) * DI + d) * 16;
    {
        const bf16x8 v0 = *reinterpret_cast<const bf16x8*>(&hentry[ob]);
        const bf16x8 v1 = *reinterpret_cast<const bf16x8*>(&hentry[ob + 8]);
        #pragma unroll
        for (int i = 0; i < 8; i++) { h[i] = (float)v0[i]; h[i + 8] = (float)v1[i]; }
    }
    const float Dv = Dp[d];
    __syncthreads();
    #pragma unroll
    for (int t = 0; t < CL; t++) {
        const float dx = dtv[t] * xcv[t];
        float y = 0.f;
        #pragma unroll
        for (int n = 0; n < 16; n++) {
            h[n] = __expf(dtv[t] * Av[n]) * h[n] + dx * Bsh[t][n];
            y += h[n] * Csh[t][n];
        }
        y += xcv[t] * Dv;
        y *= zv[t] / (1.f + __expf(-zv[t]));
        yb[(base + t) * DI + d] = (__bf16)y;
    }
}

// -------- out = x + LayerNorm(sum of NPART bf16 partials), 1-pass stats ------
__global__ __launch_bounds__(256) void ln_add(
    const float* __restrict__ x, const __bf16* __restrict__ mpart,
    const float* __restrict__ gamma, const float* __restrict__ beta,
    float* __restrict__ out)
{
    const int tok = blockIdx.x;
    const int tid = threadIdx.x;
    const int lane = tid & 63, wave = tid >> 6;
    __shared__ float red1[4], red2[4];
    __shared__ float stats[2];

    float4 v = {0.f, 0.f, 0.f, 0.f};
    #pragma unroll
    for (int p = 0; p < NPART; p++) {
        const bf16x4 mv = *reinterpret_cast<const bf16x4*>(
            &mpart[((size_t)p * NTOK + tok) * DM + tid * 4]);
        v.x += (float)mv[0]; v.y += (float)mv[1];
        v.z += (float)mv[2]; v.w += (float)mv[3];
    }
    float s1 = v.x + v.y + v.z + v.w;
    float s2 = v.x * v.x + v.y * v.y + v.z * v.z + v.w * v.w;
    #pragma unroll
    for (int o = 32; o > 0; o >>= 1) {
        s1 += __shfl_down(s1, o, 64);
        s2 += __shfl_down(s2, o, 64);
    }
    if (lane == 0) { red1[wave] = s1; red2[wave] = s2; }
    __syncthreads();
    if (tid == 0) {
        const float m1 = (red1[0] + red1[1] + red1[2] + red1[3]) * (1.f / DM);
        const float m2 = (red2[0] + red2[1] + red2[2] + red2[3]) * (1.f / DM);
        stats[0] = m1;
        stats[1] = rsqrtf(fmaxf(m2 - m1 * m1, 0.f) + 1e-6f);
    }
    __syncthreads();
    const float mu = stats[0];
    const float rs = stats[1];

    const float4 g  = reinterpret_cast<const float4*>(gamma)[tid];
    const float4 bb = reinterpret_cast<const float4*>(beta)[tid];
    const float4 xv = reinterpret_cast<const float4*>(&x[(size_t)tok * DM])[tid];
    float4 o;
    o.x = xv.x + (v.x - mu) * rs * g.x + bb.x;
    o.y = xv.y + (v.y - mu) * rs * g.y + bb.y;
    o.z = xv.z + (v.z - mu) * rs * g.z + bb.z;
    o.w = xv.w + (v.w - mu) * rs * g.w + bb.w;
    reinterpret_cast<float4*>(&out[(size_t)tok * DM])[tid] = o;
}

extern "C" void kernel_launch(void* const* d_in, const int* in_sizes, int n_in,
                              void* d_out, int out_size, void* d_ws, size_t ws_size,
                              hipStream_t stream)
{
    const float* x      = (const float*)d_in[0];
    const float* W_in   = (const float*)d_in[1];
    const float* conv_w = (const float*)d_in[2];
    const float* conv_b = (const float*)d_in[3];
    const float* W_xprj = (const float*)d_in[4];
    const float* W_dt   = (const float*)d_in[5];
    const float* b_dt   = (const float*)d_in[6];
    const float* A_log  = (const float*)d_in[7];
    const float* D_par  = (const float*)d_in[8];
    const float* W_out  = (const float*)d_in[9];
    const float* gamma  = (const float*)d_in[10];
    const float* beta   = (const float*)d_in[11];
    float* out = (float*)d_out;

    // workspace layout (byte offsets, non-aliasing, ~113 MB)
    char* w = (char*)d_ws;
    __bf16* xzb    = (__bf16*)(w + 0);          // 16 MB [NTOK][4096] (xi|z)
    __bf16* xcb    = (__bf16*)(w + 16777216);   //  8 MB [NTOK][DI]
    float*  xdbl   = (float*) (w + 25165824);   //  1 MB [NTOK][128]
    __bf16* dtb    = (__bf16*)(w + 26214400);   //  8 MB [NTOK][DI]
    __bf16* mpart  = (__bf16*)(w + 34603008);   //  8 MB [NPART][NTOK][DM]
    __bf16* hpart  = (__bf16*)(w + 51380224);   // 16 MB [NB*CK][DI][16]
    __bf16* hentry = (__bf16*)(w + 68157440);   // 16 MB [NB*CK][DI][16]
    float*  sdtb   = (float*) (w + 84934656);   //  2 MB [NB*CK][DI]
    __bf16* xb     = (__bf16*)(w + 87031808);   //  4 MB [NTOK][DM]
    __bf16* W_inT  = (__bf16*)(w + 91226112);   //  8 MB [4096][DM]
    __bf16* W_outT = (__bf16*)(w + 99614720);   //  4 MB [DM][DI]
    __bf16* W_xprT = (__bf16*)(w + 103809024);  // .5 MB [128][DI]
    __bf16* WdtT   = (__bf16*)(w + 104333312);  // .25MB [DI][64]
    __bf16* yb     = (__bf16*)(w + 104595456);  //  8 MB [NTOK][DI]

    // 0. fused prep
    prep<<<PREP_BLOCKS, 256, 0, stream>>>(
        x, W_in, W_out, W_dt, W_xprj, xb, W_inT, W_outT, WdtT, W_xprT, xdbl);

    // 1. xz = x @ W_in  (M=2048, N=4096, K=1024) -> bf16, TN=128, 8x8 XCD region
    gemm_bf16<3, 3, 128><<<dim3(32, 16, 1), 256, 0, stream>>>(
        xb, W_inT, xzb, NTOK, 2 * DI, DM, 2 * DI, nullptr);

    // 2. conv + silu -> bf16 (XCD token-chunk swizzle)
    conv_silu<<<(NTOK * DI / 8) / 256, 256, 0, stream>>>(xzb, conv_w, conv_b, xcb);

    // 3. x_dbl = xc @ W_xproj  (N=128 pad, K=2048), split-K=16, atomic f32
    gemm_bf16<1, 0, 128><<<dim3(1, 16, 16), 256, 0, stream>>>(
        xcb, W_xprT, xdbl, NTOK, XNP, DI, XNP, nullptr);

    // 4. dt = softplus(dt_r @ W_dt + b_dt) -> bf16, TN=64
    gemm_bf16<2, 0, 64><<<dim3(32, 16, 1), 256, 0, stream>>>(
        (const __bf16*)xdbl, WdtT, dtb, NTOK, DI, DTR, DI, b_dt);

    // 5. chunked selective scan (CK=128 chunks of CL=8 -> 2048 blocks A/C)
    scan_partial<<<dim3(DI / 256, CK, NB), 256, 0, stream>>>(
        xcb, xdbl, dtb, A_log, hpart, sdtb);
    scan_combine<<<NB * DI * DS / 256, 256, 0, stream>>>(A_log, sdtb, hpart, hentry);
    scan_final<<<dim3(DI / 256, CK, NB), 256, 0, stream>>>(
        xzb, xcb, xdbl, dtb, A_log, D_par, hentry, yb);

    // 6. m partials = y @ W_out  (split-K=2, TN=128 piped, bf16 partials)
    gemm_bf16<3, 1, 128><<<dim3(8, 16, NPART), 256, 0, stream>>>(
        yb, W_outT, mpart, NTOK, DM, DI, DM, nullptr);

    // 7. out = x + LN(sum of partials), single-pass stats
    ln_add<<<NTOK, 256, 0, stream>>>(x, mpart, gamma, beta, out);
}

// Round 19
// 148.641 us; speedup vs baseline: 1.0952x; 1.0076x over previous
//
#include <hip/hip_runtime.h>
#include <math.h>

#define DM   1024
#define DI   2048
#define DS   16
#define DTR  64
#define NB   2
#define SEQL 1024
#define NTOK (NB*SEQL)
#define XND  96   /* DTR + 2*DS */
#define XNP  128  /* padded xproj width */
#define CK   128  /* scan chunks */
#define CL   8    /* chunk length */
#define NPART 2   /* out-proj split-K partials */

typedef __bf16 bf16x8 __attribute__((ext_vector_type(8)));
typedef __bf16 bf16x4 __attribute__((ext_vector_type(4)));
typedef float  f32x4  __attribute__((ext_vector_type(4)));

// ------------- fused prep: zeroing + conversions + transposes ----------------
#define PREP_BLOCKS 3872

__device__ inline void trans_tile64(const float* __restrict__ W,
                                    __bf16* __restrict__ WT, int K, int N,
                                    int n0, int k0, int tid, __bf16 (*t)[65])
{
    const int tx = tid & 63, ty = tid >> 6;   // ty 0..3
    #pragma unroll
    for (int i = 0; i < 16; i++)
        t[ty * 16 + i][tx] = (__bf16)W[(size_t)(k0 + ty * 16 + i) * N + n0 + tx];
    __syncthreads();
    #pragma unroll
    for (int i = 0; i < 16; i++)
        WT[(size_t)(n0 + ty * 16 + i) * K + k0 + tx] = t[tx][ty * 16 + i];
}

__global__ __launch_bounds__(256) void prep(
    const float* __restrict__ x, const float* __restrict__ W_in,
    const float* __restrict__ W_out, const float* __restrict__ W_dt,
    const float* __restrict__ W_xprj,
    __bf16* __restrict__ xb, __bf16* __restrict__ W_inT,
    __bf16* __restrict__ W_outT, __bf16* __restrict__ WdtT,
    __bf16* __restrict__ W_xprT, float* __restrict__ xdbl)
{
    __shared__ __bf16 t[64][65];
    int bid = blockIdx.x;
    const int tid = threadIdx.x;

    if (bid < 256) {                        // R0: zero xdbl
        const int i = bid * 1024 + tid * 4;
        const float4 z = {0.f, 0.f, 0.f, 0.f};
        *reinterpret_cast<float4*>(&xdbl[i]) = z;
        return;
    }
    bid -= 256;
    if (bid < 1024) {                       // R1: cvt x -> xb
        const int e = (bid * 256 + tid) * 8;
        const float4 v0 = *reinterpret_cast<const float4*>(&x[e]);
        const float4 v1 = *reinterpret_cast<const float4*>(&x[e + 4]);
        bf16x8 o;
        o[0] = (__bf16)v0.x; o[1] = (__bf16)v0.y; o[2] = (__bf16)v0.z; o[3] = (__bf16)v0.w;
        o[4] = (__bf16)v1.x; o[5] = (__bf16)v1.y; o[6] = (__bf16)v1.z; o[7] = (__bf16)v1.w;
        *reinterpret_cast<bf16x8*>(&xb[e]) = o;
        return;
    }
    bid -= 1024;
    if (bid < 1024) {                       // R2: W_in [1024][4096] -> T
        trans_tile64(W_in, W_inT, DM, 2 * DI, (bid & 63) * 64, (bid >> 6) * 64, tid, t);
        return;
    }
    bid -= 1024;
    if (bid < 512) {                        // R3: W_out [2048][1024] -> T
        trans_tile64(W_out, W_outT, DI, DM, (bid & 15) * 64, (bid >> 4) * 64, tid, t);
        return;
    }
    bid -= 512;
    if (bid < 32) {                         // R4: W_dt [64][2048] -> T
        trans_tile64(W_dt, WdtT, DTR, DI, bid * 64, 0, tid, t);
        return;
    }
    bid -= 32;
    {                                       // R5: xproj transpose+pad
        const int idx = bid * 256 + tid;
        const int k = idx & (DI - 1);
        const int n = idx >> 11;
        W_xprT[(size_t)n * DI + k] = (n < XND) ? (__bf16)W_xprj[(size_t)k * XND + n]
                                               : (__bf16)0.f;
    }
}

// -------- bf16 MFMA GEMM, 128xTN tile, BK=64, XOR-swizzled LDS ---------------
// PIPE path (MODE 1/3): double-buffered with COUNTED vmcnt + raw s_barrier
// + T5 s_setprio around the MFMA cluster.
// MODE 1: atomicAdd f32 | 2: softplus(acc+bias)->bf16 LDS-bounce |
// 3: bf16 LDS-bounce (per-z partial offset when gridDim.z>1).
// SWZ 0: none | 1: XCD row chunks | 2: XCD col chunks | 3: XCD 8x8 region.
template<int MODE, int SWZ, int TN>
__global__ __launch_bounds__(256) void gemm_bf16(
    const __bf16* __restrict__ A, const __bf16* __restrict__ Bt,
    void* __restrict__ Cp, int M, int N, int K, int ldc,
    const float* __restrict__ bias)
{
    constexpr int NFR = TN / 32;            // n-fragments per wave per ks
    constexpr bool PIPE = (MODE != 2);
    constexpr int ASZ = 128 * 64, BSZ = TN * 64;
    constexpr int STG = (PIPE ? 2 : 1) * (ASZ + BSZ);
    constexpr int SMEM = (STG > 128 * TN) ? STG : 128 * TN;
    __shared__ __bf16 smem[SMEM];
    const int tid  = threadIdx.x;
    const int lane = tid & 63;
    const int wid  = tid >> 6;
    const int wr   = wid >> 1, wc = wid & 1;

    int bx = blockIdx.x, by = blockIdx.y;
    if (SWZ == 1 || SWZ == 2) {
        const int gx = gridDim.x, gy = gridDim.y;
        const int nxy = gx * gy;            // multiple of 8
        const int q = nxy >> 3;
        int lin = by * gx + bx;
        lin = (lin & 7) * q + (lin >> 3);
        if (SWZ == 1) { by = lin / gx; bx = lin % gx; }
        else          { bx = lin / gy; by = lin % gy; }
    } else if (SWZ == 3) {
        const int lin = by * gridDim.x + bx;
        const int r   = lin & 7;
        const int idx = lin >> 3;
        bx = (r & 3) * 8 + (idx & 7);
        by = (r >> 2) * 8 + (idx >> 3);
    }
    const int brow = by * 128, bcol = bx * TN;
    const int kper = K / gridDim.z;
    const int kbeg = blockIdx.z * kper, kend = kbeg + kper;

    f32x4 acc[4][NFR] = {};

    auto stage = [&](int buf, int k0) {
        __bf16* As = smem + buf * (ASZ + BSZ);
        __bf16* Bs = As + ASZ;
        if (MODE == 2) {
            const float* Af = reinterpret_cast<const float*>(A);
            #pragma unroll
            for (int p = 0; p < 4; p++) {
                const int i = p * 256 + tid;
                const int r = i >> 3;
                const int j = i & 7;
                const float4 v0 = *reinterpret_cast<const float4*>(
                    &Af[(size_t)(brow + r) * XNP + j * 8]);
                const float4 v1 = *reinterpret_cast<const float4*>(
                    &Af[(size_t)(brow + r) * XNP + j * 8 + 4]);
                bf16x8 o;
                o[0] = (__bf16)v0.x; o[1] = (__bf16)v0.y; o[2] = (__bf16)v0.z; o[3] = (__bf16)v0.w;
                o[4] = (__bf16)v1.x; o[5] = (__bf16)v1.y; o[6] = (__bf16)v1.z; o[7] = (__bf16)v1.w;
                *reinterpret_cast<bf16x8*>(&As[r * 64 + ((j ^ (r & 7))) * 8]) = o;
            }
        } else {
            #pragma unroll
            for (int p = 0; p < 4; p++) {
                const int i = p * 256 + tid;
                const int r = i >> 3;
                const int gc = ((i & 7) ^ (r & 7)) * 8;
                __builtin_amdgcn_global_load_lds(
                    (const __attribute__((address_space(1))) void*)(A + (size_t)(brow + r) * K + k0 + gc),
                    (__attribute__((address_space(3))) void*)(&As[i * 8]), 16, 0, 0);
            }
        }
        #pragma unroll
        for (int p = 0; p < TN / 32; p++) {
            const int i = p * 256 + tid;
            const int r = i >> 3;
            const int gc = ((i & 7) ^ (r & 7)) * 8;
            __builtin_amdgcn_global_load_lds(
                (const __attribute__((address_space(1))) void*)(Bt + (size_t)(bcol + r) * K + k0 + gc),
                (__attribute__((address_space(3))) void*)(&Bs[i * 8]), 16, 0, 0);
        }
    };

    auto compute = [&](int buf) {
        const __bf16* As = smem + buf * (ASZ + BSZ);
        const __bf16* Bs = As + ASZ;
        bf16x8 a[2][4], b[2][NFR];
        const int rA = wr * 64 + (lane & 15);
        const int rB = wc * (TN / 2) + (lane & 15);
        const int cq = lane >> 4;
        const int rx = lane & 7;
        #pragma unroll
        for (int ks = 0; ks < 2; ks++) {
            const int sl = ((ks * 4 + cq) ^ rx) * 8;
            #pragma unroll
            for (int m = 0; m < 4; m++)
                a[ks][m] = *reinterpret_cast<const bf16x8*>(&As[(rA + m * 16) * 64 + sl]);
            #pragma unroll
            for (int n = 0; n < NFR; n++)
                b[ks][n] = *reinterpret_cast<const bf16x8*>(&Bs[(rB + n * 16) * 64 + sl]);
        }
        __builtin_amdgcn_s_setprio(1);               // T5: favor MFMA wave
        #pragma unroll
        for (int ks = 0; ks < 2; ks++)
            #pragma unroll
            for (int m = 0; m < 4; m++)
                #pragma unroll
                for (int n = 0; n < NFR; n++)
                    acc[m][n] = __builtin_amdgcn_mfma_f32_16x16x32_bf16(
                        a[ks][m], b[ks][n], acc[m][n], 0, 0, 0);
        __builtin_amdgcn_s_setprio(0);
    };

    const int nt = (kend - kbeg) >> 6;
    if constexpr (PIPE) {
        constexpr int LOADS = 4 + TN / 32;   // per-thread gload_lds per stage
        stage(0, kbeg);
        int cur = 0;
        for (int t = 0; t < nt; t++) {
            if (t + 1 < nt) {
                stage(cur ^ 1, kbeg + ((t + 1) << 6));
                asm volatile("s_waitcnt vmcnt(%0)" :: "n"(LOADS) : "memory");
            } else {
                asm volatile("s_waitcnt vmcnt(0)" ::: "memory");
            }
            __builtin_amdgcn_s_barrier();          // cur's tile ready for all
            __builtin_amdgcn_sched_barrier(0);
            compute(cur);
            __builtin_amdgcn_sched_barrier(0);
            __builtin_amdgcn_s_barrier();          // all done reading cur
            cur ^= 1;
        }
    } else {
        for (int k0 = kbeg; k0 < kend; k0 += 64) {
            __syncthreads();
            stage(0, k0);
            __syncthreads();
            compute(0);
        }
    }

    const int crl = wr * 64 + (lane >> 4) * 4;   // local row base
    const int ccl = wc * (TN / 2) + (lane & 15); // local col base

    if (MODE == 1) {
        #pragma unroll
        for (int m = 0; m < 4; m++)
            #pragma unroll
            for (int n = 0; n < NFR; n++) {
                const int col = bcol + ccl + n * 16;
                #pragma unroll
                for (int j = 0; j < 4; j++)
                    atomicAdd(&((float*)Cp)[(size_t)(brow + crl + m * 16 + j) * ldc + col],
                              acc[m][n][j]);
            }
    } else {
        // ---- LDS-bounce epilogue: fragment -> LDS -> coalesced bf16x8 ----
        __syncthreads();
        __bf16* Cs = smem;
        #pragma unroll
        for (int m = 0; m < 4; m++)
            #pragma unroll
            for (int n = 0; n < NFR; n++) {
                #pragma unroll
                for (int j = 0; j < 4; j++) {
                    float v = acc[m][n][j];
                    if (MODE == 2) {
                        v += bias[bcol + ccl + n * 16];
                        v = fmaxf(v, 0.f) + log1pf(__expf(-fabsf(v)));
                    }
                    Cs[(crl + m * 16 + j) * TN + ccl + n * 16] = (__bf16)v;
                }
            }
        __syncthreads();
        __bf16* Cb = (__bf16*)Cp +
            (size_t)blockIdx.z * ((MODE == 3) ? (size_t)M * ldc : 0);
        constexpr int CHUNKS = 128 * TN / 8;
        #pragma unroll
        for (int p = 0; p < CHUNKS / 256; p++) {
            const int i = p * 256 + tid;
            const int r = i / (TN / 8);
            const int cc = (i % (TN / 8)) * 8;
            *reinterpret_cast<bf16x8*>(&Cb[(size_t)(brow + r) * ldc + bcol + cc]) =
                *reinterpret_cast<const bf16x8*>(&Cs[r * TN + cc]);
        }
    }
}

// -------- depthwise causal conv (k=4) + bias + SiLU, 8 ch/thread -------------
__global__ __launch_bounds__(256) void conv_silu(
    const __bf16* __restrict__ xzb, const float* __restrict__ conv_w,
    const float* __restrict__ conv_b, __bf16* __restrict__ xcb)
{
    const int q  = gridDim.x >> 3;
    const int sb = (blockIdx.x & 7) * q + (blockIdx.x >> 3);
    const int g  = sb * 256 + threadIdx.x;
    const int d0 = (g & 255) * 8;
    const int tok = g >> 8;
    const int t   = tok & (SEQL - 1);

    float4 wv[8];
    #pragma unroll
    for (int j = 0; j < 8; j++)
        wv[j] = *reinterpret_cast<const float4*>(&conv_w[(d0 + j) * 4]);
    float acc[8];
    {
        const float4 b0 = *reinterpret_cast<const float4*>(&conv_b[d0]);
        const float4 b1 = *reinterpret_cast<const float4*>(&conv_b[d0 + 4]);
        acc[0] = b0.x; acc[1] = b0.y; acc[2] = b0.z; acc[3] = b0.w;
        acc[4] = b1.x; acc[5] = b1.y; acc[6] = b1.z; acc[7] = b1.w;
    }
    #pragma unroll
    for (int k = 0; k < 4; k++) {
        const int tt = t + k - 3;
        if (tt >= 0) {
            const bf16x8 v = *reinterpret_cast<const bf16x8*>(
                &xzb[(size_t)(tok + k - 3) * (2 * DI) + d0]);
            #pragma unroll
            for (int j = 0; j < 8; j++) {
                const float wk = (k == 0) ? wv[j].x : (k == 1) ? wv[j].y
                               : (k == 2) ? wv[j].z : wv[j].w;
                acc[j] += (float)v[j] * wk;
            }
        }
    }
    bf16x8 o;
    #pragma unroll
    for (int j = 0; j < 8; j++) {
        const float a = acc[j];
        o[j] = (__bf16)(a / (1.f + __expf(-a)));
    }
    *reinterpret_cast<bf16x8*>(&xcb[(size_t)g * 8]) = o;
}

// -------- scan pass A: per-chunk local scan from h=0, bf16 h out -------------
__global__ __launch_bounds__(256) void scan_partial(
    const __bf16* __restrict__ xcb, const float* __restrict__ xdbl,
    const __bf16* __restrict__ dtb, const float* __restrict__ A_log,
    __bf16* __restrict__ hpart, float* __restrict__ sdtb)
{
    __shared__ float Bsh[CL][16];
    const int tid = threadIdx.x;
    const int d = blockIdx.x * 256 + tid;
    const int c = blockIdx.y, b = blockIdx.z;
    const size_t base = (size_t)b * SEQL + c * CL;
    {
        const int st = tid >> 4, sg = tid & 15;
        if (st < CL) Bsh[st][sg] = xdbl[(base + st) * XNP + DTR + sg];
    }
    float dtv[CL], xcv[CL];
    #pragma unroll
    for (int t = 0; t < CL; t++) {
        dtv[t] = (float)dtb[(base + t) * DI + d];
        xcv[t] = (float)xcb[(base + t) * DI + d];
    }
    float Av[16];
    #pragma unroll
    for (int i = 0; i < 4; i++) {
        const float4 v = *reinterpret_cast<const float4*>(&A_log[(size_t)d * 16 + i * 4]);
        Av[i*4+0] = -__expf(v.x); Av[i*4+1] = -__expf(v.y);
        Av[i*4+2] = -__expf(v.z); Av[i*4+3] = -__expf(v.w);
    }
    __syncthreads();
    float h[16] = {};
    float sdt = 0.f;
    #pragma unroll
    for (int t = 0; t < CL; t++) {
        sdt += dtv[t];
        const float dx = dtv[t] * xcv[t];
        #pragma unroll
        for (int n = 0; n < 16; n++)
            h[n] = __expf(dtv[t] * Av[n]) * h[n] + dx * Bsh[t][n];
    }
    const size_t ob = ((size_t)(b * CK + c) * DI + d) * 16;
    bf16x8 o0, o1;
    #pragma unroll
    for (int i = 0; i < 8; i++) { o0[i] = (__bf16)h[i]; o1[i] = (__bf16)h[i + 8]; }
    *reinterpret_cast<bf16x8*>(&hpart[ob])     = o0;
    *reinterpret_cast<bf16x8*>(&hpart[ob + 8]) = o1;
    sdtb[(size_t)(b * CK + c) * DI + d] = sdt;
}

// -------- scan pass B: chunk combine, hpart -> hentry (bf16), batched --------
__global__ __launch_bounds__(256) void scan_combine(
    const float* __restrict__ A_log, const float* __restrict__ sdtb,
    const __bf16* __restrict__ hpart, __bf16* __restrict__ hentry)
{
    const int idx = blockIdx.x * 256 + threadIdx.x;
    const int n = idx & 15;
    const int d = (idx >> 4) & (DI - 1);
    const int b = idx >> 15;
    const float A = -__expf(A_log[(size_t)d * 16 + n]);
    float h = 0.f;
    for (int cb = 0; cb < CK / 16; cb++) {
        float hl[16], sv[16];
        #pragma unroll
        for (int j = 0; j < 16; j++) {
            const int c = cb * 16 + j;
            hl[j] = (float)hpart[((size_t)(b * CK + c) * DI + d) * 16 + n];
            sv[j] = sdtb[(size_t)(b * CK + c) * DI + d];
        }
        #pragma unroll
        for (int j = 0; j < 16; j++) {
            const int c = cb * 16 + j;
            hentry[((size_t)(b * CK + c) * DI + d) * 16 + n] = (__bf16)h;
            h = __expf(A * sv[j]) * h + hl[j];
        }
    }
}

// -------- scan pass C: seeded re-scan, emit y (D-skip + z-gate) as bf16 ------
__global__ __launch_bounds__(256) void scan_final(
    const __bf16* __restrict__ xzb, const __bf16* __restrict__ xcb,
    const float* __restrict__ xdbl, const __bf16* __restrict__ dtb,
    const float* __restrict__ A_log, const float* __restrict__ Dp,
    const __bf16* __restrict__ hentry, __bf16* __restrict__ yb)
{
    __shared__ float Bsh[CL][16];
    __shared__ float Csh[CL][16];
    const int tid = threadIdx.x;
    const int d = blockIdx.x * 256 + tid;
    const int c = blockIdx.y, b = blockIdx.z;
    const size_t base = (size_t)b * SEQL + c * CL;
    {
        const int st = tid >> 4, sg = tid & 15;
        if (st < CL)
            Bsh[st][sg] = xdbl[(base + st) * XNP + DTR + sg];
        else if (st < 2 * CL)
            Csh[st - CL][sg] = xdbl[(base + st - CL) * XNP + DTR + DS + sg];
    }
    float dtv[CL], xcv[CL], zv[CL];
    #pragma unroll
    for (int t = 0; t < CL; t++) {
        dtv[t] = (float)dtb[(base + t) * DI + d];
        xcv[t] = (float)xcb[(base + t) * DI + d];
        zv[t]  = (float)xzb[(base + t) * (2 * DI) + DI + d];
    }
    float Av[16];
    #pragma unroll
    for (int i = 0; i < 4; i++) {
        const float4 v = *reinterpret_cast<const float4*>(&A_log[(size_t)d * 16 + i * 4]);
        Av[i*4+0] = -__expf(v.x); Av[i*4+1] = -__expf(v.y);
        Av[i*4+2] = -__expf(v.z); Av[i*4+3] = -__expf(v.w);
    }
    float h[16];
    const size_t ob = ((size_t)(b * CK + c) * DI + d) * 16;
    {
        const bf16x8 v0 = *reinterpret_cast<const bf16x8*>(&hentry[ob]);
        const bf16x8 v1 = *reinterpret_cast<const bf16x8*>(&hentry[ob + 8]);
        #pragma unroll
        for (int i = 0; i < 8; i++) { h[i] = (float)v0[i]; h[i + 8] = (float)v1[i]; }
    }
    const float Dv = Dp[d];
    __syncthreads();
    #pragma unroll
    for (int t = 0; t < CL; t++) {
        const float dx = dtv[t] * xcv[t];
        float y = 0.f;
        #pragma unroll
        for (int n = 0; n < 16; n++) {
            h[n] = __expf(dtv[t] * Av[n]) * h[n] + dx * Bsh[t][n];
            y += h[n] * Csh[t][n];
        }
        y += xcv[t] * Dv;
        y *= zv[t] / (1.f + __expf(-zv[t]));
        yb[(base + t) * DI + d] = (__bf16)y;
    }
}

// -------- out = x + LayerNorm(sum of NPART bf16 partials), 1-pass stats ------
__global__ __launch_bounds__(256) void ln_add(
    const float* __restrict__ x, const __bf16* __restrict__ mpart,
    const float* __restrict__ gamma, const float* __restrict__ beta,
    float* __restrict__ out)
{
    const int tok = blockIdx.x;
    const int tid = threadIdx.x;
    const int lane = tid & 63, wave = tid >> 6;
    __shared__ float red1[4], red2[4];
    __shared__ float stats[2];

    float4 v = {0.f, 0.f, 0.f, 0.f};
    #pragma unroll
    for (int p = 0; p < NPART; p++) {
        const bf16x4 mv = *reinterpret_cast<const bf16x4*>(
            &mpart[((size_t)p * NTOK + tok) * DM + tid * 4]);
        v.x += (float)mv[0]; v.y += (float)mv[1];
        v.z += (float)mv[2]; v.w += (float)mv[3];
    }
    float s1 = v.x + v.y + v.z + v.w;
    float s2 = v.x * v.x + v.y * v.y + v.z * v.z + v.w * v.w;
    #pragma unroll
    for (int o = 32; o > 0; o >>= 1) {
        s1 += __shfl_down(s1, o, 64);
        s2 += __shfl_down(s2, o, 64);
    }
    if (lane == 0) { red1[wave] = s1; red2[wave] = s2; }
    __syncthreads();
    if (tid == 0) {
        const float m1 = (red1[0] + red1[1] + red1[2] + red1[3]) * (1.f / DM);
        const float m2 = (red2[0] + red2[1] + red2[2] + red2[3]) * (1.f / DM);
        stats[0] = m1;
        stats[1] = rsqrtf(fmaxf(m2 - m1 * m1, 0.f) + 1e-6f);
    }
    __syncthreads();
    const float mu = stats[0];
    const float rs = stats[1];

    const float4 g  = reinterpret_cast<const float4*>(gamma)[tid];
    const float4 bb = reinterpret_cast<const float4*>(beta)[tid];
    const float4 xv = reinterpret_cast<const float4*>(&x[(size_t)tok * DM])[tid];
    float4 o;
    o.x = xv.x + (v.x - mu) * rs * g.x + bb.x;
    o.y = xv.y + (v.y - mu) * rs * g.y + bb.y;
    o.z = xv.z + (v.z - mu) * rs * g.z + bb.z;
    o.w = xv.w + (v.w - mu) * rs * g.w + bb.w;
    reinterpret_cast<float4*>(&out[(size_t)tok * DM])[tid] = o;
}

extern "C" void kernel_launch(void* const* d_in, const int* in_sizes, int n_in,
                              void* d_out, int out_size, void* d_ws, size_t ws_size,
                              hipStream_t stream)
{
    const float* x      = (const float*)d_in[0];
    const float* W_in   = (const float*)d_in[1];
    const float* conv_w = (const float*)d_in[2];
    const float* conv_b = (const float*)d_in[3];
    const float* W_xprj = (const float*)d_in[4];
    const float* W_dt   = (const float*)d_in[5];
    const float* b_dt   = (const float*)d_in[6];
    const float* A_log  = (const float*)d_in[7];
    const float* D_par  = (const float*)d_in[8];
    const float* W_out  = (const float*)d_in[9];
    const float* gamma  = (const float*)d_in[10];
    const float* beta   = (const float*)d_in[11];
    float* out = (float*)d_out;

    // workspace layout (byte offsets, non-aliasing, ~113 MB)
    char* w = (char*)d_ws;
    __bf16* xzb    = (__bf16*)(w + 0);          // 16 MB [NTOK][4096] (xi|z)
    __bf16* xcb    = (__bf16*)(w + 16777216);   //  8 MB [NTOK][DI]
    float*  xdbl   = (float*) (w + 25165824);   //  1 MB [NTOK][128]
    __bf16* dtb    = (__bf16*)(w + 26214400);   //  8 MB [NTOK][DI]
    __bf16* mpart  = (__bf16*)(w + 34603008);   //  8 MB [NPART][NTOK][DM]
    __bf16* hpart  = (__bf16*)(w + 51380224);   // 16 MB [NB*CK][DI][16]
    __bf16* hentry = (__bf16*)(w + 68157440);   // 16 MB [NB*CK][DI][16]
    float*  sdtb   = (float*) (w + 84934656);   //  2 MB [NB*CK][DI]
    __bf16* xb     = (__bf16*)(w + 87031808);   //  4 MB [NTOK][DM]
    __bf16* W_inT  = (__bf16*)(w + 91226112);   //  8 MB [4096][DM]
    __bf16* W_outT = (__bf16*)(w + 99614720);   //  4 MB [DM][DI]
    __bf16* W_xprT = (__bf16*)(w + 103809024);  // .5 MB [128][DI]
    __bf16* WdtT   = (__bf16*)(w + 104333312);  // .25MB [DI][64]
    __bf16* yb     = (__bf16*)(w + 104595456);  //  8 MB [NTOK][DI]

    // 0. fused prep
    prep<<<PREP_BLOCKS, 256, 0, stream>>>(
        x, W_in, W_out, W_dt, W_xprj, xb, W_inT, W_outT, WdtT, W_xprT, xdbl);

    // 1. xz = x @ W_in  (M=2048, N=4096, K=1024) -> bf16, TN=128, 8x8 XCD region
    gemm_bf16<3, 3, 128><<<dim3(32, 16, 1), 256, 0, stream>>>(
        xb, W_inT, xzb, NTOK, 2 * DI, DM, 2 * DI, nullptr);

    // 2. conv + silu -> bf16 (XCD token-chunk swizzle)
    conv_silu<<<(NTOK * DI / 8) / 256, 256, 0, stream>>>(xzb, conv_w, conv_b, xcb);

    // 3. x_dbl = xc @ W_xproj  (N=128 pad, K=2048), split-K=16, atomic f32
    gemm_bf16<1, 0, 128><<<dim3(1, 16, 16), 256, 0, stream>>>(
        xcb, W_xprT, xdbl, NTOK, XNP, DI, XNP, nullptr);

    // 4. dt = softplus(dt_r @ W_dt + b_dt) -> bf16, TN=64
    gemm_bf16<2, 0, 64><<<dim3(32, 16, 1), 256, 0, stream>>>(
        (const __bf16*)xdbl, WdtT, dtb, NTOK, DI, DTR, DI, b_dt);

    // 5. chunked selective scan (CK=128 chunks of CL=8 -> 2048 blocks A/C)
    scan_partial<<<dim3(DI / 256, CK, NB), 256, 0, stream>>>(
        xcb, xdbl, dtb, A_log, hpart, sdtb);
    scan_combine<<<NB * DI * DS / 256, 256, 0, stream>>>(A_log, sdtb, hpart, hentry);
    scan_final<<<dim3(DI / 256, CK, NB), 256, 0, stream>>>(
        xzb, xcb, xdbl, dtb, A_log, D_par, hentry, yb);

    // 6. m partials = y @ W_out  (split-K=2, TN=128 piped, bf16 partials)
    gemm_bf16<3, 1, 128><<<dim3(8, 16, NPART), 256, 0, stream>>>(
        yb, W_outT, mpart, NTOK, DM, DI, DM, nullptr);

    // 7. out = x + LN(sum of partials), single-pass stats
    ln_add<<<NTOK, 256, 0, stream>>>(x, mpart, gamma, beta, out);
}